// Round 8
// baseline (78.672 us; speedup 1.0000x reference)
//
#include <hip/hip_runtime.h>
#include <math.h>

// Problem constants (fixed by reference setup_inputs)
#define B_SZ 64
#define N_IN 1024
#define IDIM 64
#define NC   16
#define DC   32
#define NQ   8      // blocks per batch
#define QR   128    // rows per block
#define NTHR 512    // 8 waves

// Workspace (floats):
//  cnt : 1024 ints @ 0      per-batch counters, stride 16 (one cacheline each)
//  cs  : [64][8][64]  @ 1024   colsum partials
//  sp1 : [64][8][1024] @ 33792  xs partials iter 1
//  sp2 : [64][8][1024] @ 558080 xs partials iter 2
#define WS_CNT 0
#define WS_CS  1024
#define WS_SP1 33792
#define WS_SP2 558080

__device__ __forceinline__ void st_agent(float* p, float v) {
    __hip_atomic_store(p, v, __ATOMIC_RELAXED, __HIP_MEMORY_SCOPE_AGENT);
}
__device__ __forceinline__ float ld_agent(const float* p) {
    return __hip_atomic_load(p, __ATOMIC_RELAXED, __HIP_MEMORY_SCOPE_AGENT);
}

__global__ __launch_bounds__(1024) void k_reset(int* cnt) {
    __hip_atomic_store(&cnt[threadIdx.x], 0, __ATOMIC_RELAXED, __HIP_MEMORY_SCOPE_AGENT);
}

// x tile swizzle: element (n,i) at xT[i*QR + 4*((n>>2)^(i&7)) + (n&3)].
// - fixed i, 4 consecutive n (n%4==0): contiguous float4 (aligned)
// - 64 lanes=i reading one n-chunk: 8 bank-starts * 4 banks = all 32, 8 cyc = b128 floor
// - 32 lanes=n-chunks at fixed i: 32 distinct groups, conflict-free
#define XT4(i, n0) (&xT[(i) * QR + ((((n0) >> 2) ^ ((i) & 7)) << 2)])

__global__ __launch_bounds__(NTHR, 4)
void k_fused(const float* __restrict__ x, const float* __restrict__ W,
             float* __restrict__ out, int* __restrict__ cnt,
             float* __restrict__ cs, float* __restrict__ sp1, float* __restrict__ sp2) {
    const int b = blockIdx.x >> 3, q = blockIdx.x & 7;
    const int tid = threadIdx.x;

    // LDS total ~58.8 KB -> 2 blocks/CU
    __shared__ float __align__(16) xT[IDIM * QR];   // 32 KB swizzled x tile
    __shared__ float __align__(16) wvT[IDIM * NC];  // 4 KB [i][c], accumulated (wv0+wv1)
    __shared__ float __align__(16) aSm[NC * 132];   // 8.25 KB [c][n] logits (+colsum scratch)
    __shared__ float __align__(16) cwC[NC * 132];   // 8.25 KB [c][n] routing weights
    __shared__ float redSm[NC * IDIM];              // 4 KB reduced partials
    __shared__ float __align__(16) vSm[NC * 36];    // 2.25 KB (pad 36)

    auto barrier_batch = [&](int target) {
        __syncthreads();   // all waves' stores issued & drained before arrive
        if (tid == 0) {
            __hip_atomic_fetch_add(&cnt[b * 16], 1, __ATOMIC_RELEASE,
                                   __HIP_MEMORY_SCOPE_AGENT);
            while (__hip_atomic_load(&cnt[b * 16], __ATOMIC_ACQUIRE,
                                     __HIP_MEMORY_SCOPE_AGENT) < target)
                __builtin_amdgcn_s_sleep(2);
        }
        __syncthreads();
    };

    // ---- stage this block's 128 rows (read x from HBM exactly once)
    const float4* xb4 = reinterpret_cast<const float4*>(x + ((size_t)b * N_IN + q * QR) * IDIM);
#pragma unroll
    for (int m = 0; m < 4; m++) {
        const int f = tid + m * NTHR;
        const float4 v4 = xb4[f];
        const int n = f >> 4, i0 = (f & 15) * 4;
        xT[(i0 + 0) * QR + ((((n >> 2) ^ ((i0 + 0) & 7)) << 2) | (n & 3))] = v4.x;
        xT[(i0 + 1) * QR + ((((n >> 2) ^ ((i0 + 1) & 7)) << 2) | (n & 3))] = v4.y;
        xT[(i0 + 2) * QR + ((((n >> 2) ^ ((i0 + 2) & 7)) << 2) | (n & 3))] = v4.z;
        xT[(i0 + 3) * QR + ((((n >> 2) ^ ((i0 + 3) & 7)) << 2) | (n & 3))] = v4.w;
    }
    __syncthreads();

    // ---- colsum partial (b128 over n) -> cs[b][q][i]
    {
        const int i = tid & 63, sg = tid >> 6;
        float s = 0.f;
#pragma unroll
        for (int k = 0; k < 4; k++) {
            const float4 v4 = *reinterpret_cast<const float4*>(XT4(i, sg * 16 + k * 4));
            s += v4.x + v4.y + v4.z + v4.w;
        }
        aSm[sg * 64 + i] = s;              // scratch
    }
    __syncthreads();
    if (tid < 64) {
        float r = 0.f;
#pragma unroll
        for (int s8 = 0; s8 < 8; s8++) r += aSm[s8 * 64 + tid];
        st_agent(&cs[(b * NQ + q) * 64 + tid], r);
    }
    barrier_batch(NQ);
    if (tid < 64) {
        float r = 0.f;
#pragma unroll
        for (int k = 0; k < NQ; k++) r += ld_agent(&cs[(b * NQ + k) * 64 + tid]);
        redSm[tid] = r;
    }
    __syncthreads();

    // ---- capsule step: redSm -> v -> (wvT set/add | out)
    auto caps = [&](int mode) {   // 0: colsum/16, wvT=; 1: wvT+=; 2: out
        const int c = tid >> 5, dd = tid & 31;
        const float* Wc = W + c * (IDIM * DC) + dd;
        float s = 0.f;
#pragma unroll 8
        for (int i = 0; i < IDIM; i++) {
            const float rv = (mode == 0) ? redSm[i] : redSm[c * 64 + i];
            s += rv * Wc[i * DC];
        }
        if (mode == 0) s *= 0.0625f;
        float n2 = s * s;
#pragma unroll
        for (int m = 16; m >= 1; m >>= 1) n2 += __shfl_xor(n2, m);  // 32-lane half
        const float g = (n2 / (1.f + n2)) / (sqrtf(n2) + 1e-8f);
        if (mode == 2) {
            out[b * (NC * DC) + c * DC + dd] = g * s;
            return;
        }
        vSm[c * 36 + dd] = g * s;
        __syncthreads();
        const int c2 = tid & 15, i2 = tid >> 4;
#pragma unroll
        for (int h = 0; h < 2; h++) {
            const int i = i2 + 32 * h;
            const float4* Wr = reinterpret_cast<const float4*>(W + (size_t)(c2 * IDIM + i) * DC);
            const float4* vv = reinterpret_cast<const float4*>(vSm + c2 * 36);
            float acc = 0.f;
#pragma unroll
            for (int dq = 0; dq < 8; dq++) {
                const float4 wq = Wr[dq], vq = vv[dq];
                acc += wq.x * vq.x + wq.y * vq.y + wq.z * vq.z + wq.w * vq.w;
            }
            if (mode == 0) wvT[i * NC + c2] = acc;
            else           wvT[i * NC + c2] += acc;   // logit linearity: wv_eff = wv0+wv1
        }
        __syncthreads();
    };

    // ---- routing pass: agreement -> softmax -> xs partial -> sp[b][q][c][i]
    auto route = [&](float* sp) {
        {   // agreement: thread (r4 = 4 rows, c); xv b128, wv 2-addr broadcast
            const int r4 = tid & 31, c = tid >> 5;
            float a4[4] = {0.f, 0.f, 0.f, 0.f};
#pragma unroll 8
            for (int i = 0; i < IDIM; i++) {
                const float4 xv = *reinterpret_cast<const float4*>(XT4(i, r4 * 4));
                const float wv = wvT[i * NC + c];
                a4[0] += xv.x * wv; a4[1] += xv.y * wv;
                a4[2] += xv.z * wv; a4[3] += xv.w * wv;
            }
            *reinterpret_cast<float4*>(&aSm[c * 132 + r4 * 4]) =
                make_float4(a4[0], a4[1], a4[2], a4[3]);
        }
        __syncthreads();
        {   // softmax over 16 caps per row (4x redundant; rotated compile-time idx)
            const int n = tid & 127, grp = tid >> 7;
            float av[NC];
#pragma unroll
            for (int k = 0; k < NC; k++) av[k] = aSm[((k + grp * 4) & 15) * 132 + n];
            float mx = av[0];
#pragma unroll
            for (int k = 1; k < NC; k++) mx = fmaxf(mx, av[k]);
            float ss = 0.f;
#pragma unroll
            for (int k = 0; k < NC; k++) { av[k] = __expf(av[k] - mx); ss += av[k]; }
            const float inv = 1.f / ss;
#pragma unroll
            for (int cc = 0; cc < 4; cc++) cwC[(grp * 4 + cc) * 132 + n] = av[cc] * inv;
        }
        __syncthreads();
        {   // xs: thread (i, wave->2 caps); xv b128 column (floor), cw b128 broadcast
            const int i = tid & 63, w8 = tid >> 6;
            const int c0 = 2 * w8;
            float acc0 = 0.f, acc1 = 0.f;
#pragma unroll 4
            for (int ch = 0; ch < 32; ch++) {
                const float4 xv = *reinterpret_cast<const float4*>(XT4(i, ch * 4));
                const float4 c40 = *reinterpret_cast<const float4*>(&cwC[(c0 + 0) * 132 + ch * 4]);
                const float4 c41 = *reinterpret_cast<const float4*>(&cwC[(c0 + 1) * 132 + ch * 4]);
                acc0 += xv.x * c40.x + xv.y * c40.y + xv.z * c40.z + xv.w * c40.w;
                acc1 += xv.x * c41.x + xv.y * c41.y + xv.z * c41.z + xv.w * c41.w;
            }
            float* spq = sp + (size_t)(b * NQ + q) * 1024;
            st_agent(&spq[(c0 + 0) * 64 + i], acc0);
            st_agent(&spq[(c0 + 1) * 64 + i], acc1);
        }
    };

    // ---- pipeline
    caps(0);
    route(sp1);
    barrier_batch(2 * NQ);
    {   // reduce sp1 across 8 blocks -> redSm
        float r0 = 0.f, r1 = 0.f;
#pragma unroll
        for (int k = 0; k < NQ; k++) {
            const float* s = sp1 + (size_t)(b * NQ + k) * 1024;
            r0 += ld_agent(&s[tid]); r1 += ld_agent(&s[tid + 512]);
        }
        redSm[tid] = r0; redSm[tid + 512] = r1;
    }
    __syncthreads();
    caps(1);
    route(sp2);
    if (q != 0) {                       // producers: signal and exit
        __syncthreads();
        if (tid == 0)
            __hip_atomic_fetch_add(&cnt[b * 16], 1, __ATOMIC_RELEASE,
                                   __HIP_MEMORY_SCOPE_AGENT);
        return;
    }
    barrier_batch(3 * NQ);
    {
        float r0 = 0.f, r1 = 0.f;
#pragma unroll
        for (int k = 0; k < NQ; k++) {
            const float* s = sp2 + (size_t)(b * NQ + k) * 1024;
            r0 += ld_agent(&s[tid]); r1 += ld_agent(&s[tid + 512]);
        }
        redSm[tid] = r0; redSm[tid + 512] = r1;
    }
    __syncthreads();
    caps(2);                            // final squash -> out
}

extern "C" void kernel_launch(void* const* d_in, const int* in_sizes, int n_in,
                              void* d_out, int out_size, void* d_ws, size_t ws_size,
                              hipStream_t stream) {
    const float* x = (const float*)d_in[0];    // [64,1024,64]
    const float* W = (const float*)d_in[1];    // [16,64,32]
    float* out = (float*)d_out;                // [64,16,32]
    float* ws = (float*)d_ws;

    int*   cnt = (int*)(ws + WS_CNT);
    float* cs  = ws + WS_CS;
    float* sp1 = ws + WS_SP1;
    float* sp2 = ws + WS_SP2;

    k_reset<<<1, 1024, 0, stream>>>(cnt);
    k_fused<<<B_SZ * NQ, NTHR, 0, stream>>>(x, W, out, cnt, cs, sp1, sp2);
}

// Round 9
// 69.691 us; speedup vs baseline: 1.1289x; 1.1289x over previous
//
#include <hip/hip_runtime.h>
#include <math.h>

// Problem constants (fixed by reference setup_inputs)
#define B_SZ 64
#define N_IN 1024
#define IDIM 64
#define NC   16
#define DC   32
#define NQ   4      // blocks per batch
#define QR   256    // rows per block
#define NTHR 1024   // 16 waves
#define XS   260    // xT row stride (words): 260%32=4 -> conflict-free column b128
#define WSS  20     // wSm row stride

// Workspace (floats):
//  cnt : 64*16 ints  @ 0       per-batch counters (1 cacheline each; k_reset zeroes)
//  cs  : [64][4][64]   @ 1024    colsum partials
//  sp1 : [64][4][1024] @ 17408   xs partials iter 1
//  sp2 : [64][4][1024] @ 279552  xs partials iter 2
//  wvT : [64][1024]    @ 541696  per-batch wv_eff (written by q0, read by others)
#define WS_CNT 0
#define WS_CS  1024
#define WS_SP1 17408
#define WS_SP2 279552
#define WS_WVT 541696

__device__ __forceinline__ void st_agent(float* p, float v) {
    __hip_atomic_store(p, v, __ATOMIC_RELAXED, __HIP_MEMORY_SCOPE_AGENT);
}
__device__ __forceinline__ float ld_agent(const float* p) {
    return __hip_atomic_load(p, __ATOMIC_RELAXED, __HIP_MEMORY_SCOPE_AGENT);
}
__device__ __forceinline__ float rdlane_f(float v, int l) {
    return __int_as_float(__builtin_amdgcn_readlane(__float_as_int(v), l));
}

__global__ __launch_bounds__(1024) void k_reset(int* cnt) {
    __hip_atomic_store(&cnt[threadIdx.x], 0, __ATOMIC_RELAXED, __HIP_MEMORY_SCOPE_AGENT);
}

__global__ __launch_bounds__(NTHR, 1)
void k_fused(const float* __restrict__ x, const float* __restrict__ W,
             float* __restrict__ out, int* __restrict__ cnt,
             float* __restrict__ cs, float* __restrict__ sp1,
             float* __restrict__ sp2, float* __restrict__ wvT) {
    const int b = blockIdx.x >> 2, q = blockIdx.x & 3;
    const int tid = threadIdx.x, lane = tid & 63, wave = tid >> 6;

    // LDS 92.5 KB -> 1 block/CU, all 256 blocks co-resident
    __shared__ float xT[IDIM * XS];                 // 66.6 KB [i][n], padded stride
    __shared__ float aSm[NC * XS];                  // 16.6 KB [c][n] logits; reused as pSm
    __shared__ float __align__(16) wSm[IDIM * WSS]; // 5.1 KB [i][c] wv_eff
    __shared__ float redSm[NC * IDIM];              // 4 KB
    __shared__ float __align__(16) vSm[NC * 36];    // 2.3 KB (pad 36)

    int* mycnt = &cnt[b * 16];
    auto arrive = [&]() {
        __syncthreads();   // drains vmcnt: all agent stores complete before signal
        if (tid == 0)
            __hip_atomic_fetch_add(mycnt, 1, __ATOMIC_RELEASE, __HIP_MEMORY_SCOPE_AGENT);
    };
    auto wait_ge = [&](int t) {
        if (tid == 0)
            while (__hip_atomic_load(mycnt, __ATOMIC_ACQUIRE,
                                     __HIP_MEMORY_SCOPE_AGENT) < t)
                __builtin_amdgcn_s_sleep(2);
        __syncthreads();
    };

    // ---- stage 256 rows into padded [i][n] tile (x read from HBM exactly once)
    const float4* xb4 = reinterpret_cast<const float4*>(x + ((size_t)b * N_IN + q * QR) * IDIM);
#pragma unroll
    for (int m = 0; m < 4; m++) {
        const int f = tid + m * NTHR;
        const float4 v4 = xb4[f];
        const int n = f >> 4, i0 = (f & 15) * 4;
        xT[(i0 + 0) * XS + n] = v4.x;
        xT[(i0 + 1) * XS + n] = v4.y;
        xT[(i0 + 2) * XS + n] = v4.z;
        xT[(i0 + 3) * XS + n] = v4.w;
    }
    __syncthreads();

    // ---- colsum partial: wave sg sums its 16 rows via b128
    {
        const int i = lane, sg = wave;
        float s = 0.f;
#pragma unroll
        for (int j = 0; j < 4; j++) {
            const float4 v4 = *reinterpret_cast<const float4*>(&xT[i * XS + sg * 16 + j * 4]);
            s += v4.x + v4.y + v4.z + v4.w;
        }
        redSm[sg * 64 + i] = s;
    }
    __syncthreads();
    if (tid < 64) {
        float r = 0.f;
#pragma unroll
        for (int sg = 0; sg < 16; sg++) r += redSm[sg * 64 + tid];
        st_agent(&cs[(b * NQ + q) * 64 + tid], r);
    }
    arrive();                                    // -> 4

    // ---- capsule step (q0 only): redSm -> v -> wSm (+wvT global) | out
    auto caps = [&](int mode) {   // 0: colsum/16, set; 1: accumulate; 2: out
        if (tid < 512) {
            const int c = tid >> 5, dd = tid & 31;
            const float* Wc = W + c * (IDIM * DC) + dd;
            float s = 0.f;
#pragma unroll 8
            for (int i = 0; i < IDIM; i++) {
                const float rv = (mode == 0) ? redSm[i] : redSm[c * 64 + i];
                s += rv * Wc[i * DC];
            }
            if (mode == 0) s *= 0.0625f;
            float n2 = s * s;
#pragma unroll
            for (int m = 16; m >= 1; m >>= 1) n2 += __shfl_xor(n2, m);  // 32-lane half
            const float g = (n2 / (1.f + n2)) / (sqrtf(n2) + 1e-8f);
            if (mode == 2) out[b * (NC * DC) + c * DC + dd] = g * s;
            else           vSm[c * 36 + dd] = g * s;
        }
        __syncthreads();
        if (mode == 2) return;
        const int i = tid >> 4, c = tid & 15;
        const float4* Wr = reinterpret_cast<const float4*>(W + (size_t)(c * IDIM + i) * DC);
        const float4* vv = reinterpret_cast<const float4*>(&vSm[c * 36]);
        float acc = 0.f;
#pragma unroll
        for (int dq = 0; dq < 8; dq++) {
            const float4 wq = Wr[dq], vq = vv[dq];
            acc += wq.x * vq.x + wq.y * vq.y + wq.z * vq.z + wq.w * vq.w;
        }
        const float wnew = (mode == 0) ? acc : (wSm[i * WSS + c] + acc);
        wSm[i * WSS + c] = wnew;                     // logit linearity: wv_eff = wv0+wv1
        st_agent(&wvT[(size_t)b * 1024 + i * 16 + c], wnew);
        // arrive() follows at call site (its syncthreads orders wSm for route)
    };

    if (q == 0) {
        wait_ge(4);
        if (tid < 64) {
            float r = 0.f;
#pragma unroll
            for (int k = 0; k < NQ; k++) r += ld_agent(&cs[(b * NQ + k) * 64 + tid]);
            redSm[tid] = r;
        }
        __syncthreads();
        caps(0);
        arrive();                                // -> 5
    } else {
        wait_ge(5);
        wSm[(tid >> 4) * WSS + (tid & 15)] = ld_agent(&wvT[(size_t)b * 1024 + tid]);
        __syncthreads();
    }

    // ---- routing pass: agreement(b128) -> softmax(regs) -> xs(readlane) -> sp
    auto route = [&](float* sp) {
        if (tid < 256) {   // agreement: (r4 = 4 rows, cq = 4 caps), waves 0-3
            const int r4 = tid & 63, cq = tid >> 6;
            float ac[4][4] = {{0.f}};
#pragma unroll
            for (int i = 0; i < IDIM; i++) {
                const float4 xv = *reinterpret_cast<const float4*>(&xT[i * XS + r4 * 4]);
                const float4 w4 = *reinterpret_cast<const float4*>(&wSm[i * WSS + cq * 4]);
                ac[0][0] += xv.x * w4.x; ac[0][1] += xv.x * w4.y;
                ac[0][2] += xv.x * w4.z; ac[0][3] += xv.x * w4.w;
                ac[1][0] += xv.y * w4.x; ac[1][1] += xv.y * w4.y;
                ac[1][2] += xv.y * w4.z; ac[1][3] += xv.y * w4.w;
                ac[2][0] += xv.z * w4.x; ac[2][1] += xv.z * w4.y;
                ac[2][2] += xv.z * w4.z; ac[2][3] += xv.z * w4.w;
                ac[3][0] += xv.w * w4.x; ac[3][1] += xv.w * w4.y;
                ac[3][2] += xv.w * w4.z; ac[3][3] += xv.w * w4.w;
            }
#pragma unroll
            for (int cc = 0; cc < 4; cc++)
                *reinterpret_cast<float4*>(&aSm[(cq * 4 + cc) * XS + r4 * 4]) =
                    make_float4(ac[0][cc], ac[1][cc], ac[2][cc], ac[3][cc]);
        }
        __syncthreads();
        // softmax: thread (n = tid&255, grp = tid>>8); cw kept in registers
        const int n = tid & 255, grp = tid >> 8;
        float av[NC];
#pragma unroll
        for (int k = 0; k < NC; k++) av[k] = aSm[((k + grp * 4) & 15) * XS + n];
        float mx = av[0];
#pragma unroll
        for (int k = 1; k < NC; k++) mx = fmaxf(mx, av[k]);
        float ss = 0.f;
#pragma unroll
        for (int k = 0; k < NC; k++) { av[k] = __expf(av[k] - mx); ss += av[k]; }
        const float inv = 1.f / ss;
        const float cw0 = av[0] * inv, cw1 = av[1] * inv;
        const float cw2 = av[2] * inv, cw3 = av[3] * inv;   // caps grp*4..+3, row n
        __syncthreads();                         // aSm reads done -> becomes pSm
        // xs: wave (grp = wave>>2, rq = wave&3) == softmax mapping (rq = n>>6).
        // lane reinterpreted as i; cw for row rq*64+nl lives in lane nl -> readlane.
        {
            const int rq = wave & 3;
            float a0 = 0.f, a1 = 0.f, a2 = 0.f, a3 = 0.f;
#pragma unroll
            for (int j = 0; j < 16; j++) {
                const float4 xv = *reinterpret_cast<const float4*>(
                    &xT[lane * XS + rq * 64 + j * 4]);
#pragma unroll
                for (int l = 0; l < 4; l++) {
                    const int nl = j * 4 + l;
                    const float xc = (l == 0) ? xv.x : (l == 1) ? xv.y
                                   : (l == 2) ? xv.z : xv.w;
                    a0 += rdlane_f(cw0, nl) * xc;
                    a1 += rdlane_f(cw1, nl) * xc;
                    a2 += rdlane_f(cw2, nl) * xc;
                    a3 += rdlane_f(cw3, nl) * xc;
                }
            }
            aSm[(grp * 4 + 0) * XS + rq * 64 + lane] = a0;
            aSm[(grp * 4 + 1) * XS + rq * 64 + lane] = a1;
            aSm[(grp * 4 + 2) * XS + rq * 64 + lane] = a2;
            aSm[(grp * 4 + 3) * XS + rq * 64 + lane] = a3;
        }
        __syncthreads();
        // reduce the 4 row-quarter partials; store sp[b][q][c*64+i]
        const int c = tid >> 6, ii = tid & 63;
        const float v = aSm[c * XS + ii] + aSm[c * XS + 64 + ii] +
                        aSm[c * XS + 128 + ii] + aSm[c * XS + 192 + ii];
        st_agent(&sp[(size_t)(b * NQ + q) * 1024 + tid], v);
    };

    // ---- iter 1
    route(sp1);
    arrive();                                    // -> 9
    if (q == 0) {
        wait_ge(9);
        {
            float r = 0.f;
#pragma unroll
            for (int k = 0; k < NQ; k++) r += ld_agent(&sp1[(size_t)(b * NQ + k) * 1024 + tid]);
            redSm[tid] = r;
        }
        __syncthreads();
        caps(1);
        arrive();                                // -> 10
    } else {
        wait_ge(10);
        wSm[(tid >> 4) * WSS + (tid & 15)] = ld_agent(&wvT[(size_t)b * 1024 + tid]);
        __syncthreads();
    }
    // ---- iter 2
    route(sp2);
    arrive();                                    // -> 14
    if (q != 0) return;
    wait_ge(14);
    {
        float r = 0.f;
#pragma unroll
        for (int k = 0; k < NQ; k++) r += ld_agent(&sp2[(size_t)(b * NQ + k) * 1024 + tid]);
        redSm[tid] = r;
    }
    __syncthreads();
    caps(2);                                     // final squash -> out
}

extern "C" void kernel_launch(void* const* d_in, const int* in_sizes, int n_in,
                              void* d_out, int out_size, void* d_ws, size_t ws_size,
                              hipStream_t stream) {
    const float* x = (const float*)d_in[0];    // [64,1024,64]
    const float* W = (const float*)d_in[1];    // [16,64,32]
    float* out = (float*)d_out;                // [64,16,32]
    float* ws = (float*)d_ws;

    int*   cnt = (int*)(ws + WS_CNT);
    float* cs  = ws + WS_CS;
    float* sp1 = ws + WS_SP1;
    float* sp2 = ws + WS_SP2;
    float* wvT = ws + WS_WVT;

    k_reset<<<1, 1024, 0, stream>>>(cnt);
    k_fused<<<B_SZ * NQ, NTHR, 0, stream>>>(x, W, out, cnt, cs, sp1, sp2, wvT);
}

// Round 10
// 56.236 us; speedup vs baseline: 1.3990x; 1.2393x over previous
//
#include <hip/hip_runtime.h>
#include <math.h>

// Problem constants (fixed by reference setup_inputs)
#define B_SZ 64
#define N_IN 1024
#define IDIM 64
#define NC   16
#define DC   32
#define NQ   4      // blocks per batch
#define QR   256    // rows per block
#define NTHR 1024   // 16 waves
#define XS   260    // xT row stride: 260%32=4 -> column b128 at bank floor
#define CWS  20     // cw row stride [n][16+4]

typedef float f2 __attribute__((ext_vector_type(2)));   // -> v_pk_fma_f32

// Workspace (floats):
//  cnt : 64*16 ints  @ 0       per-batch counters (1 cacheline apart)
//  cs  : [64][4][64]   @ 1024    colsum partials
//  sp1 : [64][4][1024] @ 17408   xs partials iter 1
//  sp2 : [64][4][1024] @ 279552  xs partials iter 2
#define WS_CNT 0
#define WS_CS  1024
#define WS_SP1 17408
#define WS_SP2 279552

__device__ __forceinline__ void st_agent(float* p, float v) {
    __hip_atomic_store(p, v, __ATOMIC_RELAXED, __HIP_MEMORY_SCOPE_AGENT);
}
__device__ __forceinline__ float ld_agent(const float* p) {
    return __hip_atomic_load(p, __ATOMIC_RELAXED, __HIP_MEMORY_SCOPE_AGENT);
}

__global__ __launch_bounds__(1024) void k_reset(int* cnt) {
    __hip_atomic_store(&cnt[threadIdx.x], 0, __ATOMIC_RELAXED, __HIP_MEMORY_SCOPE_AGENT);
}

__global__ __launch_bounds__(NTHR, 1)
void k_fused(const float* __restrict__ x, const float* __restrict__ W,
             float* __restrict__ out, int* __restrict__ cnt,
             float* __restrict__ cs, float* __restrict__ sp1, float* __restrict__ sp2) {
    const int b = blockIdx.x >> 2, q = blockIdx.x & 3;
    const int tid = threadIdx.x, lane = tid & 63, wave = tid >> 6;

    // LDS ~111.5 KB -> 1 block/CU; 256 blocks co-resident on 256 CUs
    __shared__ float xT[IDIM * XS];                 // 65 KB [i][n] padded
    __shared__ float aSm[NC * XS];                  // 16.3 KB [c][n] logits; reused as pSm
    __shared__ float __align__(16) cwC[QR * CWS];   // 20 KB [n][c] routing weights
    __shared__ float __align__(16) wSm[IDIM * 16];  // 4 KB [i][c] wv_eff (wv0 / wv0+wv1)
    __shared__ float redSm[NC * IDIM];              // 4 KB reduced partials
    __shared__ float __align__(16) vSm[NC * 36];    // 2.3 KB (pad 36)

    int* mycnt = &cnt[b * 16];
    auto arrive = [&]() {
        __syncthreads();   // all agent stores of this block done before signal
        if (tid == 0)
            __hip_atomic_fetch_add(mycnt, 1, __ATOMIC_RELEASE, __HIP_MEMORY_SCOPE_AGENT);
    };
    auto wait_ge = [&](int t) {
        if (tid == 0)
            while (__hip_atomic_load(mycnt, __ATOMIC_ACQUIRE,
                                     __HIP_MEMORY_SCOPE_AGENT) < t)
                __builtin_amdgcn_s_sleep(2);
        __syncthreads();
    };

    // ---- stage 256 rows into [i][n] tile (x read from HBM exactly once)
    const float4* xb4 = reinterpret_cast<const float4*>(x + ((size_t)b * N_IN + q * QR) * IDIM);
#pragma unroll
    for (int m = 0; m < 4; m++) {
        const int f = tid + m * NTHR;
        const float4 v4 = xb4[f];
        const int n = f >> 4, i0 = (f & 15) * 4;
        xT[(i0 + 0) * XS + n] = v4.x;
        xT[(i0 + 1) * XS + n] = v4.y;
        xT[(i0 + 2) * XS + n] = v4.z;
        xT[(i0 + 3) * XS + n] = v4.w;
    }
    __syncthreads();

    // ---- colsum partial: wave w sums rows w*16..+15 (b128), lane = i
    {
        float s = 0.f;
#pragma unroll
        for (int j = 0; j < 4; j++) {
            const float4 v4 = *reinterpret_cast<const float4*>(&xT[lane * XS + wave * 16 + j * 4]);
            s += v4.x + v4.y + v4.z + v4.w;
        }
        redSm[wave * 64 + lane] = s;
    }
    __syncthreads();
    if (tid < 64) {
        float r = 0.f;
#pragma unroll
        for (int w2 = 0; w2 < 16; w2++) r += redSm[w2 * 64 + tid];
        st_agent(&cs[(b * NQ + q) * 64 + tid], r);
    }
    arrive();                                    // -> 4
    wait_ge(4);
    if (tid < 64) {
        float r = 0.f;
#pragma unroll
        for (int k = 0; k < NQ; k++) r += ld_agent(&cs[(b * NQ + k) * 64 + tid]);
        redSm[tid] = r;
    }
    __syncthreads();

    // ---- capsule step (redundant in every block; all phases full-width)
    auto caps = [&](int mode) {   // 0: colsum/16, wSm=; 1: wSm+=; 2: out (q0)
        if (tid < 512) {
            const int c = tid >> 5, dd = tid & 31;
            const float* Wc = W + c * (IDIM * DC) + dd;
            float s = 0.f;
#pragma unroll 8
            for (int i = 0; i < IDIM; i++) {
                const float rv = (mode == 0) ? redSm[i] : redSm[c * 64 + i];
                s += rv * Wc[i * DC];
            }
            if (mode == 0) s *= 0.0625f;
            float n2 = s * s;
#pragma unroll
            for (int m = 16; m >= 1; m >>= 1) n2 += __shfl_xor(n2, m);  // 32-lane half
            const float g = (n2 / (1.f + n2)) / (sqrtf(n2) + 1e-8f);
            if (mode == 2) { if (q == 0) out[b * (NC * DC) + c * DC + dd] = g * s; }
            else           vSm[c * 36 + dd] = g * s;
        }
        __syncthreads();
        if (mode == 2) return;
        const int i = tid >> 4, c = tid & 15;   // 64 i x 16 c
        const float4* Wr = reinterpret_cast<const float4*>(W + (size_t)(c * IDIM + i) * DC);
        const float4* vv = reinterpret_cast<const float4*>(&vSm[c * 36]);
        float acc = 0.f;
#pragma unroll
        for (int dq = 0; dq < 8; dq++) {
            const float4 wq = Wr[dq], vq = vv[dq];
            acc += wq.x * vq.x + wq.y * vq.y + wq.z * vq.z + wq.w * vq.w;
        }
        if (mode == 0) wSm[i * 16 + c] = acc;
        else           wSm[i * 16 + c] += acc;   // logit linearity: wv_eff = wv0 + wv1
        __syncthreads();
    };

    // ---- routing pass: agreement -> softmax -> xs -> sp[b][q][c*64+i]
    auto route = [&](float* sp) {
        const int row = tid & 255, grp = tid >> 8;      // grp wave-uniform
        {   // agreement: caps grp*4..+3 for row; pk-fma pairs
            f2 a01 = {0.f, 0.f}, a23 = {0.f, 0.f};
#pragma unroll 8
            for (int i = 0; i < IDIM; i++) {
                const float xv = xT[i * XS + row];                       // conflict-free b32
                const float4 w4 = *reinterpret_cast<const float4*>(&wSm[i * 16 + grp * 4]);
                const f2 xv2 = {xv, xv};
                const f2 w01 = {w4.x, w4.y}, w23 = {w4.z, w4.w};
                a01 += xv2 * w01;                                        // v_pk_fma_f32
                a23 += xv2 * w23;
            }
            aSm[(grp * 4 + 0) * XS + row] = a01.x;
            aSm[(grp * 4 + 1) * XS + row] = a01.y;
            aSm[(grp * 4 + 2) * XS + row] = a23.x;
            aSm[(grp * 4 + 3) * XS + row] = a23.y;
        }
        __syncthreads();
        {   // softmax over 16 caps per row (rotated compile-time idx); write cw n-major
            float av[NC];
#pragma unroll
            for (int k = 0; k < NC; k++) av[k] = aSm[((k + grp * 4) & 15) * XS + row];
            float mx = av[0];
#pragma unroll
            for (int k = 1; k < NC; k++) mx = fmaxf(mx, av[k]);
            float ss = 0.f;
#pragma unroll
            for (int k = 0; k < NC; k++) { av[k] = __expf(av[k] - mx); ss += av[k]; }
            const float inv = 1.f / ss;
            const float4 cw4 = make_float4(av[0] * inv, av[1] * inv, av[2] * inv, av[3] * inv);
            *reinterpret_cast<float4*>(&cwC[row * CWS + grp * 4]) = cw4;
        }
        __syncthreads();
        {   // xs: wave (cg = wave>>2, rq = wave&3): caps cg*4..+3, rows rq*64..+63, lane = i
            const int cg = wave >> 2, rq = wave & 3;
            f2 acc01 = {0.f, 0.f}, acc23 = {0.f, 0.f};
#pragma unroll 4
            for (int j = 0; j < 16; j++) {
                const int n0 = rq * 64 + j * 4;
                const float4 xv = *reinterpret_cast<const float4*>(&xT[lane * XS + n0]);  // b128 floor
                const float4 c0 = *reinterpret_cast<const float4*>(&cwC[(n0 + 0) * CWS + cg * 4]);
                const float4 c1 = *reinterpret_cast<const float4*>(&cwC[(n0 + 1) * CWS + cg * 4]);
                const float4 c2 = *reinterpret_cast<const float4*>(&cwC[(n0 + 2) * CWS + cg * 4]);
                const float4 c3 = *reinterpret_cast<const float4*>(&cwC[(n0 + 3) * CWS + cg * 4]);
                f2 xv2;
                xv2 = (f2){xv.x, xv.x}; acc01 += xv2 * (f2){c0.x, c0.y}; acc23 += xv2 * (f2){c0.z, c0.w};
                xv2 = (f2){xv.y, xv.y}; acc01 += xv2 * (f2){c1.x, c1.y}; acc23 += xv2 * (f2){c1.z, c1.w};
                xv2 = (f2){xv.z, xv.z}; acc01 += xv2 * (f2){c2.x, c2.y}; acc23 += xv2 * (f2){c2.z, c2.w};
                xv2 = (f2){xv.w, xv.w}; acc01 += xv2 * (f2){c3.x, c3.y}; acc23 += xv2 * (f2){c3.z, c3.w};
            }
            float* pSm = aSm;                   // aSm reads all done (post-sync)
            pSm[rq * 1024 + (cg * 4 + 0) * 64 + lane] = acc01.x;
            pSm[rq * 1024 + (cg * 4 + 1) * 64 + lane] = acc01.y;
            pSm[rq * 1024 + (cg * 4 + 2) * 64 + lane] = acc23.x;
            pSm[rq * 1024 + (cg * 4 + 3) * 64 + lane] = acc23.y;
        }
        __syncthreads();
        const float val = aSm[tid] + aSm[1024 + tid] + aSm[2048 + tid] + aSm[3072 + tid];
        st_agent(&sp[(size_t)(b * NQ + q) * 1024 + tid], val);
    };

    // ---- pipeline
    caps(0);
    route(sp1);
    arrive();                                    // -> 8
    wait_ge(8);
    {
        float r = 0.f;
#pragma unroll
        for (int k = 0; k < NQ; k++) r += ld_agent(&sp1[(size_t)(b * NQ + k) * 1024 + tid]);
        redSm[tid] = r;
    }
    __syncthreads();
    caps(1);
    route(sp2);
    arrive();                                    // -> 12
    if (q != 0) return;
    wait_ge(12);
    {
        float r = 0.f;
#pragma unroll
        for (int k = 0; k < NQ; k++) r += ld_agent(&sp2[(size_t)(b * NQ + k) * 1024 + tid]);
        redSm[tid] = r;
    }
    __syncthreads();
    caps(2);                                     // final squash -> out (q0)
}

extern "C" void kernel_launch(void* const* d_in, const int* in_sizes, int n_in,
                              void* d_out, int out_size, void* d_ws, size_t ws_size,
                              hipStream_t stream) {
    const float* x = (const float*)d_in[0];    // [64,1024,64]
    const float* W = (const float*)d_in[1];    // [16,64,32]
    float* out = (float*)d_out;                // [64,16,32]
    float* ws = (float*)d_ws;

    int*   cnt = (int*)(ws + WS_CNT);
    float* cs  = ws + WS_CS;
    float* sp1 = ws + WS_SP1;
    float* sp2 = ws + WS_SP2;

    k_reset<<<1, 1024, 0, stream>>>(cnt);
    k_fused<<<B_SZ * NQ, NTHR, 0, stream>>>(x, W, out, cnt, cs, sp1, sp2);
}

// Round 11
// 52.010 us; speedup vs baseline: 1.5126x; 1.0812x over previous
//
#include <hip/hip_runtime.h>
#include <math.h>

// Problem constants (fixed by reference setup_inputs)
#define B_SZ 64
#define N_IN 1024
#define IDIM 64
#define NC   16
#define DC   32
#define NQ   4      // blocks per batch
#define QR   256    // rows per block
#define NTHR 1024   // 16 waves
#define XS   260    // xT row stride: 260%32=4 -> column b128 at bank floor

typedef float f2 __attribute__((ext_vector_type(2)));   // -> v_pk_fma_f32

// Workspace (floats):
//  cnt : 64*16 ints  @ 0       per-batch counters (1 cacheline apart)
//  cs  : [64][4][64]   @ 1024    colsum partials
//  sp1 : [64][4][1024] @ 17408   xs partials iter 1
//  sp2 : [64][4][1024] @ 279552  xs partials iter 2
#define WS_CNT 0
#define WS_CS  1024
#define WS_SP1 17408
#define WS_SP2 279552

__device__ __forceinline__ void st_agent(float* p, float v) {
    __hip_atomic_store(p, v, __ATOMIC_RELAXED, __HIP_MEMORY_SCOPE_AGENT);
}
__device__ __forceinline__ float ld_agent(const float* p) {
    return __hip_atomic_load(p, __ATOMIC_RELAXED, __HIP_MEMORY_SCOPE_AGENT);
}
__device__ __forceinline__ float rdlane_f(float v, int l) {
    return __int_as_float(__builtin_amdgcn_readlane(__float_as_int(v), l));
}

__global__ __launch_bounds__(1024) void k_reset(int* cnt) {
    __hip_atomic_store(&cnt[threadIdx.x], 0, __ATOMIC_RELAXED, __HIP_MEMORY_SCOPE_AGENT);
}

__global__ __launch_bounds__(NTHR, 1)
void k_fused(const float* __restrict__ x, const float* __restrict__ W,
             float* __restrict__ out, int* __restrict__ cnt,
             float* __restrict__ cs, float* __restrict__ sp1, float* __restrict__ sp2) {
    // XCD co-location: blocks {b, b+64, b+128, b+192} all have bid%8 == b%8 ->
    // same XCD under round-robin dispatch (perf heuristic; correctness is
    // agent-scope atomics regardless of placement).
    const int b = blockIdx.x & 63, q = blockIdx.x >> 6;
    const int tid = threadIdx.x, lane = tid & 63, wave = tid >> 6;

    // LDS ~107.5 KB -> 1 block/CU; 256 blocks co-resident on 256 CUs
    __shared__ float xT[IDIM * XS];                 // 65 KB [i][n] padded
    __shared__ float aSm[NC * XS];                  // 16.3 KB [c][n] logits
    __shared__ float pSm[4096];                     // 16 KB xs partials [rq][c*64+i]
    __shared__ float __align__(16) wSm[IDIM * 16];  // 4 KB [i][c] wv_eff (wv0 / wv0+wv1)
    __shared__ float redSm[NC * IDIM];              // 4 KB reduced partials
    __shared__ float __align__(16) vSm[NC * 36];    // 2.3 KB (pad 36)

    int* mycnt = &cnt[b * 16];
    auto arrive = [&]() {
        __syncthreads();   // all agent stores of this block done before signal
        if (tid == 0)
            __hip_atomic_fetch_add(mycnt, 1, __ATOMIC_RELEASE, __HIP_MEMORY_SCOPE_AGENT);
    };
    auto wait_ge = [&](int t) {
        if (tid == 0)
            while (__hip_atomic_load(mycnt, __ATOMIC_ACQUIRE,
                                     __HIP_MEMORY_SCOPE_AGENT) < t)
                __builtin_amdgcn_s_sleep(1);
        __syncthreads();
    };

    // ---- stage 256 rows into [i][n] tile (x read from HBM exactly once)
    const float4* xb4 = reinterpret_cast<const float4*>(x + ((size_t)b * N_IN + q * QR) * IDIM);
#pragma unroll
    for (int m = 0; m < 4; m++) {
        const int f = tid + m * NTHR;
        const float4 v4 = xb4[f];
        const int n = f >> 4, i0 = (f & 15) * 4;
        xT[(i0 + 0) * XS + n] = v4.x;
        xT[(i0 + 1) * XS + n] = v4.y;
        xT[(i0 + 2) * XS + n] = v4.z;
        xT[(i0 + 3) * XS + n] = v4.w;
    }
    __syncthreads();

    // ---- colsum partial: wave w sums rows w*16..+15 (b128), lane = i
    {
        float s = 0.f;
#pragma unroll
        for (int j = 0; j < 4; j++) {
            const float4 v4 = *reinterpret_cast<const float4*>(&xT[lane * XS + wave * 16 + j * 4]);
            s += v4.x + v4.y + v4.z + v4.w;
        }
        redSm[wave * 64 + lane] = s;
    }
    __syncthreads();
    if (tid < 64) {
        float r = 0.f;
#pragma unroll
        for (int w2 = 0; w2 < 16; w2++) r += redSm[w2 * 64 + tid];
        st_agent(&cs[(b * NQ + q) * 64 + tid], r);
    }
    arrive();                                    // -> 4
    wait_ge(4);
    if (tid < 64) {
        float r = 0.f;
#pragma unroll
        for (int k = 0; k < NQ; k++) r += ld_agent(&cs[(b * NQ + k) * 64 + tid]);
        redSm[tid] = r;
    }
    __syncthreads();

    // ---- capsule step (redundant in every block; all phases full-width)
    auto caps = [&](int mode) {   // 0: colsum/16, wSm=; 1: wSm+=; 2: out (q0)
        if (tid < 512) {
            const int c = tid >> 5, dd = tid & 31;
            const float* Wc = W + c * (IDIM * DC) + dd;
            float s = 0.f;
#pragma unroll 8
            for (int i = 0; i < IDIM; i++) {
                const float rv = (mode == 0) ? redSm[i] : redSm[c * 64 + i];
                s += rv * Wc[i * DC];
            }
            if (mode == 0) s *= 0.0625f;
            float n2 = s * s;
#pragma unroll
            for (int m = 16; m >= 1; m >>= 1) n2 += __shfl_xor(n2, m);  // 32-lane half
            const float g = (n2 / (1.f + n2)) / (sqrtf(n2) + 1e-8f);
            if (mode == 2) { if (q == 0) out[b * (NC * DC) + c * DC + dd] = g * s; }
            else           vSm[c * 36 + dd] = g * s;
        }
        __syncthreads();
        if (mode == 2) return;
        const int i = tid >> 4, c = tid & 15;   // 64 i x 16 c
        const float4* Wr = reinterpret_cast<const float4*>(W + (size_t)(c * IDIM + i) * DC);
        const float4* vv = reinterpret_cast<const float4*>(&vSm[c * 36]);
        float acc = 0.f;
#pragma unroll
        for (int dq = 0; dq < 8; dq++) {
            const float4 wq = Wr[dq], vq = vv[dq];
            acc += wq.x * vq.x + wq.y * vq.y + wq.z * vq.z + wq.w * vq.w;
        }
        if (mode == 0) wSm[i * 16 + c] = acc;
        else           wSm[i * 16 + c] += acc;   // logit linearity: wv_eff = wv0 + wv1
        __syncthreads();
    };

    // ---- routing pass: agreement -> softmax(regs) -> xs(readlane) -> sp
    auto route = [&](float* sp) {
        const int row = tid & 255, grp = tid >> 8;      // grp wave-uniform
        {   // agreement: caps grp*4..+3 for row; pk-fma pairs
            f2 a01 = {0.f, 0.f}, a23 = {0.f, 0.f};
#pragma unroll 8
            for (int i = 0; i < IDIM; i++) {
                const float xv = xT[i * XS + row];                       // conflict-free b32
                const float4 w4 = *reinterpret_cast<const float4*>(&wSm[i * 16 + grp * 4]);
                const f2 xv2 = {xv, xv};
                a01 += xv2 * (f2){w4.x, w4.y};                           // v_pk_fma_f32
                a23 += xv2 * (f2){w4.z, w4.w};
            }
            aSm[(grp * 4 + 0) * XS + row] = a01.x;
            aSm[(grp * 4 + 1) * XS + row] = a01.y;
            aSm[(grp * 4 + 2) * XS + row] = a23.x;
            aSm[(grp * 4 + 3) * XS + row] = a23.y;
        }
        __syncthreads();
        // softmax over 16 caps per row (rotated compile-time idx); cw stays in REGISTERS
        float cw0, cw1, cw2, cw3;
        {
            float av[NC];
#pragma unroll
            for (int k = 0; k < NC; k++) av[k] = aSm[((k + grp * 4) & 15) * XS + row];
            float mx = av[0];
#pragma unroll
            for (int k = 1; k < NC; k++) mx = fmaxf(mx, av[k]);
            float ss = 0.f;
#pragma unroll
            for (int k = 0; k < NC; k++) { av[k] = __expf(av[k] - mx); ss += av[k]; }
            const float inv = 1.f / ss;
            cw0 = av[0] * inv; cw1 = av[1] * inv; cw2 = av[2] * inv; cw3 = av[3] * inv;
        }
        // xs: NO sync needed (reads xT + same-wave regs, writes dedicated pSm).
        // wave (cg = wave>>2, rq = wave&3): caps cg*4..+3, rows rq*64..+63, lane = i.
        // cw for row rq*64+nl lives in lane nl of THIS wave -> v_readlane (SGPR bcast).
        {
            const int cg = wave >> 2, rq = wave & 3;
            float a0 = 0.f, a1 = 0.f, a2 = 0.f, a3 = 0.f;
#pragma unroll
            for (int j = 0; j < 16; j++) {
                const float4 xv = *reinterpret_cast<const float4*>(
                    &xT[lane * XS + rq * 64 + j * 4]);                   // b128 floor
#pragma unroll
                for (int l = 0; l < 4; l++) {
                    const int nl = j * 4 + l;
                    const float xc = (l == 0) ? xv.x : (l == 1) ? xv.y
                                   : (l == 2) ? xv.z : xv.w;
                    a0 += rdlane_f(cw0, nl) * xc;
                    a1 += rdlane_f(cw1, nl) * xc;
                    a2 += rdlane_f(cw2, nl) * xc;
                    a3 += rdlane_f(cw3, nl) * xc;
                }
            }
            pSm[rq * 1024 + (cg * 4 + 0) * 64 + lane] = a0;
            pSm[rq * 1024 + (cg * 4 + 1) * 64 + lane] = a1;
            pSm[rq * 1024 + (cg * 4 + 2) * 64 + lane] = a2;
            pSm[rq * 1024 + (cg * 4 + 3) * 64 + lane] = a3;
        }
        __syncthreads();
        // reduce the 4 row-quarter partials; store sp[b][q][c*64+i]
        const float val = pSm[tid] + pSm[1024 + tid] + pSm[2048 + tid] + pSm[3072 + tid];
        st_agent(&sp[(size_t)(b * NQ + q) * 1024 + tid], val);
    };

    // ---- pipeline
    caps(0);
    route(sp1);
    arrive();                                    // -> 8
    wait_ge(8);
    {
        float r = 0.f;
#pragma unroll
        for (int k = 0; k < NQ; k++) r += ld_agent(&sp1[(size_t)(b * NQ + k) * 1024 + tid]);
        redSm[tid] = r;
    }
    __syncthreads();
    caps(1);
    route(sp2);
    arrive();                                    // -> 12
    if (q != 0) return;
    wait_ge(12);
    {
        float r = 0.f;
#pragma unroll
        for (int k = 0; k < NQ; k++) r += ld_agent(&sp2[(size_t)(b * NQ + k) * 1024 + tid]);
        redSm[tid] = r;
    }
    __syncthreads();
    caps(2);                                     // final squash -> out (q0)
}

extern "C" void kernel_launch(void* const* d_in, const int* in_sizes, int n_in,
                              void* d_out, int out_size, void* d_ws, size_t ws_size,
                              hipStream_t stream) {
    const float* x = (const float*)d_in[0];    // [64,1024,64]
    const float* W = (const float*)d_in[1];    // [16,64,32]
    float* out = (float*)d_out;                // [64,16,32]
    float* ws = (float*)d_ws;

    int*   cnt = (int*)(ws + WS_CNT);
    float* cs  = ws + WS_CS;
    float* sp1 = ws + WS_SP1;
    float* sp2 = ws + WS_SP2;

    k_reset<<<1, 1024, 0, stream>>>(cnt);
    k_fused<<<B_SZ * NQ, NTHR, 0, stream>>>(x, W, out, cnt, cs, sp1, sp2);
}

// Round 12
// 49.924 us; speedup vs baseline: 1.5758x; 1.0418x over previous
//
#include <hip/hip_runtime.h>
#include <math.h>

// Problem constants (fixed by reference setup_inputs)
#define B_SZ 64
#define N_IN 1024
#define IDIM 64
#define NC   16
#define DC   32
#define NQ   4      // blocks per batch
#define QR   256    // rows per block
#define NTHR 1024   // 16 waves
#define XS   68     // xT row stride [n][i]: 68%32=4 -> 8 bank-starts, b128 floor
#define AS   20     // aSmT / pSm / wSm row stride (20%32: 8 bank-starts)

// Workspace (floats):
//  cnt : 64*16 ints  @ 0       per-batch counters (1 cacheline apart)
//  cs  : [64][4][64]   @ 1024    colsum partials
//  sp1 : [64][4][1024] @ 17408   xs partials iter 1
//  sp2 : [64][4][1024] @ 279552  xs partials iter 2
#define WS_CNT 0
#define WS_CS  1024
#define WS_SP1 17408
#define WS_SP2 279552

__device__ __forceinline__ void st_agent(float* p, float v) {
    __hip_atomic_store(p, v, __ATOMIC_RELAXED, __HIP_MEMORY_SCOPE_AGENT);
}
__device__ __forceinline__ float ld_agent(const float* p) {
    return __hip_atomic_load(p, __ATOMIC_RELAXED, __HIP_MEMORY_SCOPE_AGENT);
}
__device__ __forceinline__ float rdlane_f(float v, int l) {
    return __int_as_float(__builtin_amdgcn_readlane(__float_as_int(v), l));
}

__global__ __launch_bounds__(1024) void k_reset(int* cnt) {
    __hip_atomic_store(&cnt[threadIdx.x], 0, __ATOMIC_RELAXED, __HIP_MEMORY_SCOPE_AGENT);
}

__global__ __launch_bounds__(NTHR, 1)
void k_fused(const float* __restrict__ x, const float* __restrict__ W,
             float* __restrict__ out, int* __restrict__ cnt,
             float* __restrict__ cs, float* __restrict__ sp1, float* __restrict__ sp2) {
    // XCD co-location: blocks {b, b+64, b+128, b+192} share bid%8 -> same XCD
    // under round-robin dispatch (heuristic; correctness from agent atomics).
    const int b = blockIdx.x & 63, q = blockIdx.x >> 6;
    const int tid = threadIdx.x, lane = tid & 63, wave = tid >> 6;
    const int row = tid & 255, grp = tid >> 8;   // grp == wave>>2 (wave-uniform)
    const int rq = wave & 3;

    // LDS ~122 KB -> 1 block/CU; 256 blocks co-resident on 256 CUs
    __shared__ float __align__(16) xT[QR * XS];       // 69.6 KB [n][i]
    __shared__ float __align__(16) aSmT[QR * AS];     // 20.5 KB [n][c] logits
    __shared__ float __align__(16) pSm[4 * 64 * AS];  // 20.5 KB [rq][i][c] xs partials
    __shared__ float __align__(16) wSm[IDIM * AS];    // 5.1 KB [i][c] wv_eff
    __shared__ float redSm[NC * IDIM];                // 4 KB reduced partials
    __shared__ float __align__(16) vSm[NC * 36];      // 2.3 KB (pad 36)

    int* mycnt = &cnt[b * 16];
    auto arrive = [&]() {
        __syncthreads();   // drains vmcnt: agent stores visible before signal
        if (tid == 0)
            __hip_atomic_fetch_add(mycnt, 1, __ATOMIC_RELEASE, __HIP_MEMORY_SCOPE_AGENT);
    };
    auto wait_ge = [&](int t) {
        if (tid == 0)
            while (__hip_atomic_load(mycnt, __ATOMIC_ACQUIRE,
                                     __HIP_MEMORY_SCOPE_AGENT) < t)
                __builtin_amdgcn_s_sleep(1);
        __syncthreads();
    };

    // ---- stage 256 rows into [n][i] tile: 4 conflict-free ds_write_b128/thread
    const float4* xb4 = reinterpret_cast<const float4*>(x + ((size_t)b * N_IN + q * QR) * IDIM);
#pragma unroll
    for (int m = 0; m < 4; m++) {
        const int f = tid + m * NTHR;
        const float4 v4 = xb4[f];
        const int n = f >> 4, i0 = (f & 15) * 4;
        *reinterpret_cast<float4*>(&xT[n * XS + i0]) = v4;
    }
    __syncthreads();

    // ---- colsum partial: wave w sums rows w*16..+15 at i = lane (coalesced b32)
    {
        float s = 0.f;
#pragma unroll
        for (int t = 0; t < 16; t++) s += xT[(wave * 16 + t) * XS + lane];
        redSm[wave * 64 + lane] = s;
    }
    __syncthreads();
    if (tid < 64) {
        float r = 0.f;
#pragma unroll
        for (int w2 = 0; w2 < 16; w2++) r += redSm[w2 * 64 + tid];
        st_agent(&cs[(b * NQ + q) * 64 + tid], r);
    }
    arrive();                                    // -> 4
    wait_ge(4);
    if (tid < 64) {
        float r = 0.f;
#pragma unroll
        for (int k = 0; k < NQ; k++) r += ld_agent(&cs[(b * NQ + k) * 64 + tid]);
        redSm[tid] = r;
    }
    __syncthreads();

    // ---- capsule step (redundant in every block)
    auto caps = [&](int mode) {   // 0: colsum/16, wSm=; 1: wSm+=; 2: out (q0)
        if (tid < 512) {
            const int c = tid >> 5, dd = tid & 31;
            const float* Wc = W + c * (IDIM * DC) + dd;
            float s = 0.f;
#pragma unroll 8
            for (int i = 0; i < IDIM; i++) {
                const float rv = (mode == 0) ? redSm[i] : redSm[c * 64 + i];
                s += rv * Wc[i * DC];
            }
            if (mode == 0) s *= 0.0625f;
            float n2 = s * s;
#pragma unroll
            for (int m = 16; m >= 1; m >>= 1) n2 += __shfl_xor(n2, m);  // 32-lane half
            const float g = (n2 / (1.f + n2)) / (sqrtf(n2) + 1e-8f);
            if (mode == 2) { if (q == 0) out[b * (NC * DC) + c * DC + dd] = g * s; }
            else           vSm[c * 36 + dd] = g * s;
        }
        __syncthreads();
        if (mode == 2) return;
        const int i = tid >> 4, c = tid & 15;   // 64 i x 16 c
        const float4* Wr = reinterpret_cast<const float4*>(W + (size_t)(c * IDIM + i) * DC);
        const float4* vv = reinterpret_cast<const float4*>(&vSm[c * 36]);
        float acc = 0.f;
#pragma unroll
        for (int dq = 0; dq < 8; dq++) {
            const float4 wq = Wr[dq], vq = vv[dq];
            acc += wq.x * vq.x + wq.y * vq.y + wq.z * vq.z + wq.w * vq.w;
        }
        if (mode == 0) wSm[i * AS + c] = acc;
        else           wSm[i * AS + c] += acc;   // logit linearity: wv_eff = wv0 + wv1
        __syncthreads();
    };

    // ---- routing pass: agreement(b128+readlane) -> softmax(b128) -> xs(readlane)
    auto route = [&](float* sp) -> float {
        // one-time preload: lane l holds wv[i=l][grp*4..+3] (b128, 8-start floor)
        const float4 wr4 = *reinterpret_cast<const float4*>(&wSm[lane * AS + grp * 4]);
        {   // agreement: 16 x b128 + 256 readlane-fma; caps grp*4..+3, row = tid&255
            float a0 = 0.f, a1 = 0.f, a2 = 0.f, a3 = 0.f;
#pragma unroll
            for (int iq = 0; iq < 16; iq++) {
                const float4 xv = *reinterpret_cast<const float4*>(&xT[row * XS + iq * 4]);
#pragma unroll
                for (int j = 0; j < 4; j++) {
                    const int i = iq * 4 + j;
                    const float xc = (j == 0) ? xv.x : (j == 1) ? xv.y
                                   : (j == 2) ? xv.z : xv.w;
                    a0 += rdlane_f(wr4.x, i) * xc;
                    a1 += rdlane_f(wr4.y, i) * xc;
                    a2 += rdlane_f(wr4.z, i) * xc;
                    a3 += rdlane_f(wr4.w, i) * xc;
                }
            }
            *reinterpret_cast<float4*>(&aSmT[row * AS + grp * 4]) =
                make_float4(a0, a1, a2, a3);
        }
        __syncthreads();
        // softmax over 16 caps per row: 4 b128 reads; cw via uniform grp if-chain
        float cw0, cw1, cw2, cw3;
        {
            const float4 q0 = *reinterpret_cast<const float4*>(&aSmT[row * AS + 0]);
            const float4 q1 = *reinterpret_cast<const float4*>(&aSmT[row * AS + 4]);
            const float4 q2 = *reinterpret_cast<const float4*>(&aSmT[row * AS + 8]);
            const float4 q3 = *reinterpret_cast<const float4*>(&aSmT[row * AS + 12]);
            float av[NC] = {q0.x, q0.y, q0.z, q0.w, q1.x, q1.y, q1.z, q1.w,
                            q2.x, q2.y, q2.z, q2.w, q3.x, q3.y, q3.z, q3.w};
            float mx = av[0];
#pragma unroll
            for (int k = 1; k < NC; k++) mx = fmaxf(mx, av[k]);
            float ss = 0.f;
#pragma unroll
            for (int k = 0; k < NC; k++) { av[k] = __expf(av[k] - mx); ss += av[k]; }
            const float inv = 1.f / ss;
            if (grp == 0)      { cw0 = av[0];  cw1 = av[1];  cw2 = av[2];  cw3 = av[3];  }
            else if (grp == 1) { cw0 = av[4];  cw1 = av[5];  cw2 = av[6];  cw3 = av[7];  }
            else if (grp == 2) { cw0 = av[8];  cw1 = av[9];  cw2 = av[10]; cw3 = av[11]; }
            else               { cw0 = av[12]; cw1 = av[13]; cw2 = av[14]; cw3 = av[15]; }
            cw0 *= inv; cw1 *= inv; cw2 *= inv; cw3 *= inv;
        }
        // xs: NO sync (reads xT + same-wave regs, writes pSm). wave (grp, rq):
        // caps grp*4..+3, rows rq*64..+63, lane = i; cw for row rq*64+nl in lane nl.
        {
            float s0 = 0.f, s1 = 0.f, s2 = 0.f, s3 = 0.f;
#pragma unroll
            for (int nl = 0; nl < 64; nl++) {
                const float xv = xT[(rq * 64 + nl) * XS + lane];   // coalesced b32
                s0 += rdlane_f(cw0, nl) * xv;
                s1 += rdlane_f(cw1, nl) * xv;
                s2 += rdlane_f(cw2, nl) * xv;
                s3 += rdlane_f(cw3, nl) * xv;
            }
            *reinterpret_cast<float4*>(&pSm[(rq * 64 + lane) * AS + grp * 4]) =
                make_float4(s0, s1, s2, s3);
        }
        __syncthreads();
        // reduce 4 rq partials: thread (c = wave, i = lane); store sp[b][q][c*64+i]
        const float val = pSm[(0 * 64 + lane) * AS + wave] +
                          pSm[(1 * 64 + lane) * AS + wave] +
                          pSm[(2 * 64 + lane) * AS + wave] +
                          pSm[(3 * 64 + lane) * AS + wave];
        st_agent(&sp[(size_t)(b * NQ + q) * 1024 + tid], val);
        return val;
    };

    // ---- pipeline
    caps(0);
    const float v1 = route(sp1);
    arrive();                                    // -> 8
    wait_ge(8);
    {
        float r = v1;                            // own partial from registers
#pragma unroll
        for (int k = 0; k < NQ; k++)
            if (k != q) r += ld_agent(&sp1[(size_t)(b * NQ + k) * 1024 + tid]);
        redSm[tid] = r;
    }
    __syncthreads();
    caps(1);
    const float v2 = route(sp2);
    arrive();                                    // -> 12
    if (q != 0) return;
    wait_ge(12);
    {
        float r = v2;
#pragma unroll
        for (int k = 0; k < NQ; k++)
            if (k != q) r += ld_agent(&sp2[(size_t)(b * NQ + k) * 1024 + tid]);
        redSm[tid] = r;
    }
    __syncthreads();
    caps(2);                                     // final squash -> out (q0)
}

extern "C" void kernel_launch(void* const* d_in, const int* in_sizes, int n_in,
                              void* d_out, int out_size, void* d_ws, size_t ws_size,
                              hipStream_t stream) {
    const float* x = (const float*)d_in[0];    // [64,1024,64]
    const float* W = (const float*)d_in[1];    // [16,64,32]
    float* out = (float*)d_out;                // [64,16,32]
    float* ws = (float*)d_ws;

    int*   cnt = (int*)(ws + WS_CNT);
    float* cs  = ws + WS_CS;
    float* sp1 = ws + WS_SP1;
    float* sp2 = ws + WS_SP2;

    k_reset<<<1, 1024, 0, stream>>>(cnt);
    k_fused<<<B_SZ * NQ, NTHR, 0, stream>>>(x, W, out, cnt, cs, sp1, sp2);
}

// Round 14
// 49.798 us; speedup vs baseline: 1.5798x; 1.0025x over previous
//
#include <hip/hip_runtime.h>
#include <math.h>

// Problem constants (fixed by reference setup_inputs)
#define B_SZ 64
#define N_IN 1024
#define IDIM 64
#define NC   16
#define DC   32
#define NCH  16     // 64-row chunks per batch
#define XSS  68     // xT row stride [n][i]: 68%32=4 -> b128 floor patterns
#define ASS  20     // aSmT row stride

// Workspace layout (floats). No zero-init needed: every region is fully
// written before read. No atomics, no spin barriers, no memset.
//  csp : [64][16][64]   @ 0        colsum partials
//  sp1 : [64][16][1024] @ 65536    xs partials iter 1
//  sp2 : [64][16][1024] @ 1114112  xs partials iter 2
//  wv0 : [64][1024]     @ 2162688  wv(v0), layout [b][i*16+c]
//  wvE : [64][1024]     @ 2228224  wv(v0)+wv(v1)  (logits linear in wv -> no blog)
#define WS_CSP 0
#define WS_SP1 65536
#define WS_SP2 1114112
#define WS_WV0 2162688
#define WS_WVE 2228224

__device__ __forceinline__ float rdlane_f(float v, int l) {
    return __int_as_float(__builtin_amdgcn_readlane(__float_as_int(v), l));
}

// -------- K1: colsum partials csp[b][ch][i] = sum of 64 rows
__global__ __launch_bounds__(256) void k_colsum(const float* __restrict__ x,
                                                float* __restrict__ csp) {
    const int b = blockIdx.y, ch = blockIdx.x;
    const int i = threadIdx.x & 63, p = threadIdx.x >> 6;
    const float* xb = x + ((size_t)b * N_IN + ch * 64) * IDIM;
    float s = 0.f;
#pragma unroll
    for (int t = 0; t < 16; t++) s += xb[(p * 16 + t) * IDIM + i];   // coalesced
    __shared__ float red[4][64];
    red[p][i] = s;
    __syncthreads();
    if (p == 0)
        csp[(b * NCH + ch) * 64 + i] = red[0][i] + red[1][i] + red[2][i] + red[3][i];
}

// -------- K2/K4/K6: capsule step, one block per batch (512 thr).
// MODE 0: red[i] from csp, s = red@W/16, squash, wv -> wv0
// MODE 1: red[c][i] from sp1, squash, wvE = wv + wv0
// MODE 2: red[c][i] from sp2, squash -> out
template<int MODE>
__global__ __launch_bounds__(512) void k_caps(const float* __restrict__ partIn,
                                              const float* __restrict__ W,
                                              const float* __restrict__ wvPrev,
                                              float* __restrict__ outp) {
    const int b = blockIdx.x, tid = threadIdx.x;
    __shared__ float redSm[NC * IDIM];
    __shared__ float __align__(16) vSm[NC * 36];    // pad 36 vs bank conflicts

    if (MODE == 0) {
        if (tid < 64) {
            float r = 0.f;
#pragma unroll
            for (int k = 0; k < NCH; k++) r += partIn[(b * NCH + k) * 64 + tid];
            redSm[tid] = r;
        }
    } else {
#pragma unroll
        for (int m = 0; m < 2; m++) {
            const int o = tid + m * 512;
            float r = 0.f;
#pragma unroll
            for (int k = 0; k < NCH; k++)
                r += partIn[(size_t)(b * NCH + k) * 1024 + o];
            redSm[o] = r;
        }
    }
    __syncthreads();

    // s[c][dd], thread = (c = tid>>5, dd = tid&31); squash over 32-lane group
    const int c = tid >> 5, dd = tid & 31;
    const float* Wc = W + c * (IDIM * DC) + dd;
    float s = 0.f;
#pragma unroll 8
    for (int i = 0; i < IDIM; i++) {
        const float rv = (MODE == 0) ? redSm[i] : redSm[c * 64 + i];
        s += rv * Wc[i * DC];
    }
    if (MODE == 0) s *= 0.0625f;
    float n2 = s * s;
#pragma unroll
    for (int m = 16; m >= 1; m >>= 1) n2 += __shfl_xor(n2, m);   // 32-lane half = one c
    const float g = (n2 / (1.f + n2)) / (sqrtf(n2) + 1e-8f);
    if (MODE == 2) {
        outp[b * (NC * DC) + c * DC + dd] = g * s;
        return;
    }
    vSm[c * 36 + dd] = g * s;
    __syncthreads();

    // wv[i][c2] = sum_d W[c2][i][d] * v[c2][d]; layout [b][i*16+c2]
    const int c2 = tid & 15, ib = tid >> 4;
#pragma unroll
    for (int h = 0; h < 2; h++) {
        const int i = ib + 32 * h;
        const float4* Wr = reinterpret_cast<const float4*>(W + (size_t)(c2 * IDIM + i) * DC);
        const float4* vv = reinterpret_cast<const float4*>(&vSm[c2 * 36]);
        float acc = 0.f;
#pragma unroll
        for (int dq = 0; dq < 8; dq++) {
            const float4 wq = Wr[dq], vq = vv[dq];
            acc += wq.x * vq.x + wq.y * vq.y + wq.z * vq.z + wq.w * vq.w;
        }
        const int oi = i * NC + c2;
        outp[b * 1024 + oi] = acc + ((MODE == 1) ? wvPrev[b * 1024 + oi] : 0.f);
    }
}

// -------- K3/K5: routing pass. Block = (b, 64-row chunk), 256 thr = 4 waves.
// agreement (b128 x + readlane wv) -> softmax (regs) -> xs (readlane cw) -> sp.
// Wave grp owns caps grp*4..+3; lane = row in phases 1-2, lane = i in xs.
__global__ __launch_bounds__(256) void k_route(const float* __restrict__ x,
                                               const float* __restrict__ wvp,
                                               float* __restrict__ sp) {
    const int b = blockIdx.y, ch = blockIdx.x;
    const int tid = threadIdx.x, lane = tid & 63, grp = tid >> 6;

    __shared__ float __align__(16) xT[64 * XSS];     // 17.4 KB [n][i]
    __shared__ float __align__(16) aSmT[64 * ASS];   // 5.1 KB [n][c] logits

    // wv fragment: lane l holds wv[i=l][grp*4..+3] (one-time global read, L2-hot)
    const float4 wr4 = *reinterpret_cast<const float4*>(
        &wvp[(size_t)b * 1024 + lane * NC + grp * 4]);

    // stage 64 rows: 4 conflict-free ds_write_b128 / thread
    const float4* xb4 = reinterpret_cast<const float4*>(x + ((size_t)b * N_IN + ch * 64) * IDIM);
#pragma unroll
    for (int m = 0; m < 4; m++) {
        const int f = tid + m * 256;
        const float4 v4 = xb4[f];
        const int n = f >> 4, i0 = (f & 15) * 4;
        *reinterpret_cast<float4*>(&xT[n * XSS + i0]) = v4;
    }
    __syncthreads();

    // agreement: row = lane, caps grp*4..+3; 16 b128 + readlane-fma
    {
        float a0 = 0.f, a1 = 0.f, a2 = 0.f, a3 = 0.f;
#pragma unroll
        for (int iq = 0; iq < 16; iq++) {
            const float4 xv = *reinterpret_cast<const float4*>(&xT[lane * XSS + iq * 4]);
#pragma unroll
            for (int j = 0; j < 4; j++) {
                const int i = iq * 4 + j;
                const float xc = (j == 0) ? xv.x : (j == 1) ? xv.y
                               : (j == 2) ? xv.z : xv.w;
                a0 += rdlane_f(wr4.x, i) * xc;
                a1 += rdlane_f(wr4.y, i) * xc;
                a2 += rdlane_f(wr4.z, i) * xc;
                a3 += rdlane_f(wr4.w, i) * xc;
            }
        }
        *reinterpret_cast<float4*>(&aSmT[lane * ASS + grp * 4]) =
            make_float4(a0, a1, a2, a3);
    }
    __syncthreads();

    // softmax over 16 caps per row (4 b128 reads); keep this wave's 4 cw in regs
    float cw0, cw1, cw2, cw3;
    {
        const float4 q0 = *reinterpret_cast<const float4*>(&aSmT[lane * ASS + 0]);
        const float4 q1 = *reinterpret_cast<const float4*>(&aSmT[lane * ASS + 4]);
        const float4 q2 = *reinterpret_cast<const float4*>(&aSmT[lane * ASS + 8]);
        const float4 q3 = *reinterpret_cast<const float4*>(&aSmT[lane * ASS + 12]);
        float av[NC] = {q0.x, q0.y, q0.z, q0.w, q1.x, q1.y, q1.z, q1.w,
                        q2.x, q2.y, q2.z, q2.w, q3.x, q3.y, q3.z, q3.w};
        float mx = av[0];
#pragma unroll
        for (int k = 1; k < NC; k++) mx = fmaxf(mx, av[k]);
        float ss = 0.f;
#pragma unroll
        for (int k = 0; k < NC; k++) { av[k] = __expf(av[k] - mx); ss += av[k]; }
        const float inv = 1.f / ss;
        if (grp == 0)      { cw0 = av[0];  cw1 = av[1];  cw2 = av[2];  cw3 = av[3];  }
        else if (grp == 1) { cw0 = av[4];  cw1 = av[5];  cw2 = av[6];  cw3 = av[7];  }
        else if (grp == 2) { cw0 = av[8];  cw1 = av[9];  cw2 = av[10]; cw3 = av[11]; }
        else               { cw0 = av[12]; cw1 = av[13]; cw2 = av[14]; cw3 = av[15]; }
        cw0 *= inv; cw1 *= inv; cw2 *= inv; cw3 *= inv;
    }

    // xs: NO sync (reads xT + same-wave regs). lane = i; cw for row nl in lane nl.
    // Final partial lands directly in registers -> direct coalesced store.
    {
        float s0 = 0.f, s1 = 0.f, s2 = 0.f, s3 = 0.f;
#pragma unroll
        for (int nl = 0; nl < 64; nl++) {
            const float xv = xT[nl * XSS + lane];        // conflict-free b32
            s0 += rdlane_f(cw0, nl) * xv;
            s1 += rdlane_f(cw1, nl) * xv;
            s2 += rdlane_f(cw2, nl) * xv;
            s3 += rdlane_f(cw3, nl) * xv;
        }
        float* spq = sp + (size_t)(b * NCH + ch) * 1024;
        spq[(grp * 4 + 0) * 64 + lane] = s0;
        spq[(grp * 4 + 1) * 64 + lane] = s1;
        spq[(grp * 4 + 2) * 64 + lane] = s2;
        spq[(grp * 4 + 3) * 64 + lane] = s3;
    }
}

extern "C" void kernel_launch(void* const* d_in, const int* in_sizes, int n_in,
                              void* d_out, int out_size, void* d_ws, size_t ws_size,
                              hipStream_t stream) {
    const float* x = (const float*)d_in[0];    // [64,1024,64]
    const float* W = (const float*)d_in[1];    // [16,64,32]
    float* out = (float*)d_out;                // [64,16,32]
    float* ws = (float*)d_ws;

    float* csp = ws + WS_CSP;
    float* sp1 = ws + WS_SP1;
    float* sp2 = ws + WS_SP2;
    float* wv0 = ws + WS_WV0;
    float* wvE = ws + WS_WVE;

    // iter 0: colsum partials -> v0 -> wv0
    k_colsum<<<dim3(NCH, B_SZ), 256, 0, stream>>>(x, csp);
    k_caps<0><<<B_SZ, 512, 0, stream>>>(csp, W, wv0, wv0);
    // iter 1: logits = x.wv0 -> softmax -> sp1; v1 -> wvE = wv0 + wv(v1)
    k_route<<<dim3(NCH, B_SZ), 256, 0, stream>>>(x, wv0, sp1);
    k_caps<1><<<B_SZ, 512, 0, stream>>>(sp1, W, wv0, wvE);
    // iter 2: logits = x.wvE = b2 -> softmax -> sp2; final squash -> out
    k_route<<<dim3(NCH, B_SZ), 256, 0, stream>>>(x, wvE, sp2);
    k_caps<2><<<B_SZ, 512, 0, stream>>>(sp2, W, wvE, out);
}

// Round 16
// 48.104 us; speedup vs baseline: 1.6354x; 1.0352x over previous
//
#include <hip/hip_runtime.h>
#include <math.h>

// Problem constants (fixed by reference setup_inputs)
#define B_SZ 64
#define N_IN 1024
#define IDIM 64
#define NC   16
#define DC   32
#define NQ   4      // blocks per batch
#define QR   256    // rows per block
#define NTHR 1024   // 16 waves
#define XS   68     // xT row stride [n][i]: 68%32=4 -> b128 floor patterns
#define AS   20     // aSmT / pSm / wSm row stride

// Workspace (floats):
//  cnt : 64*16 ints  @ 0       per-batch counters (1 cacheline apart)
//  cs  : [64][4][64]   @ 1024    colsum partials (agent scope, within k_phase1)
//  sp1 : [64][4][1024] @ 17408   xs partials iter 1 (PLAIN: kernel-boundary sync)
//  sp2 : [64][4][1024] @ 279552  xs partials iter 2 (agent scope, within k_phase2)
//  wv0 : [64][1024]    @ 541696  wv(v0) (plain; q0 writes in k1, all read in k2)
#define WS_CNT 0
#define WS_CS  1024
#define WS_SP1 17408
#define WS_SP2 279552
#define WS_WV0 541696

__device__ __forceinline__ void st_agent(float* p, float v) {
    __hip_atomic_store(p, v, __ATOMIC_RELAXED, __HIP_MEMORY_SCOPE_AGENT);
}
__device__ __forceinline__ float ld_agent(const float* p) {
    return __hip_atomic_load(p, __ATOMIC_RELAXED, __HIP_MEMORY_SCOPE_AGENT);
}
__device__ __forceinline__ float rdlane_f(float v, int l) {
    return __int_as_float(__builtin_amdgcn_readlane(__float_as_int(v), l));
}

__global__ __launch_bounds__(1024) void k_reset(int* cnt) {
    __hip_atomic_store(&cnt[threadIdx.x], 0, __ATOMIC_RELAXED, __HIP_MEMORY_SCOPE_AGENT);
}

// ---- shared building blocks (round-12-proven inner code) ----

// stage 256 rows into [n][i] tile: 4 conflict-free ds_write_b128/thread
__device__ __forceinline__ void stage_x(const float* __restrict__ x, float* xT,
                                        int b, int q, int tid) {
    const float4* xb4 = reinterpret_cast<const float4*>(x + ((size_t)b * N_IN + q * QR) * IDIM);
#pragma unroll
    for (int m = 0; m < 4; m++) {
        const int f = tid + m * NTHR;
        const float4 v4 = xb4[f];
        const int n = f >> 4, i0 = (f & 15) * 4;
        *reinterpret_cast<float4*>(&xT[n * XS + i0]) = v4;
    }
}

// routing pass: agreement(b128+readlane) -> softmax(regs) -> xs(readlane) -> val
// caller stores val (plain or agent). tid mapping identical to round 12.
__device__ __forceinline__ float route_pass(const float* xT, const float* wSm,
                                            float* aSmT, float* pSm,
                                            int tid, int lane, int wave,
                                            int row, int grp, int rq) {
    const float4 wr4 = *reinterpret_cast<const float4*>(&wSm[lane * AS + grp * 4]);
    {   // agreement: caps grp*4..+3 for row; 16 b128 + readlane-fma
        float a0 = 0.f, a1 = 0.f, a2 = 0.f, a3 = 0.f;
#pragma unroll
        for (int iq = 0; iq < 16; iq++) {
            const float4 xv = *reinterpret_cast<const float4*>(&xT[row * XS + iq * 4]);
#pragma unroll
            for (int j = 0; j < 4; j++) {
                const int i = iq * 4 + j;
                const float xc = (j == 0) ? xv.x : (j == 1) ? xv.y
                               : (j == 2) ? xv.z : xv.w;
                a0 += rdlane_f(wr4.x, i) * xc;
                a1 += rdlane_f(wr4.y, i) * xc;
                a2 += rdlane_f(wr4.z, i) * xc;
                a3 += rdlane_f(wr4.w, i) * xc;
            }
        }
        *reinterpret_cast<float4*>(&aSmT[row * AS + grp * 4]) =
            make_float4(a0, a1, a2, a3);
    }
    __syncthreads();
    // softmax over 16 caps per row; cw via uniform grp if-chain (regs only)
    float cw0, cw1, cw2, cw3;
    {
        const float4 q0 = *reinterpret_cast<const float4*>(&aSmT[row * AS + 0]);
        const float4 q1 = *reinterpret_cast<const float4*>(&aSmT[row * AS + 4]);
        const float4 q2 = *reinterpret_cast<const float4*>(&aSmT[row * AS + 8]);
        const float4 q3 = *reinterpret_cast<const float4*>(&aSmT[row * AS + 12]);
        float av[NC] = {q0.x, q0.y, q0.z, q0.w, q1.x, q1.y, q1.z, q1.w,
                        q2.x, q2.y, q2.z, q2.w, q3.x, q3.y, q3.z, q3.w};
        float mx = av[0];
#pragma unroll
        for (int k = 1; k < NC; k++) mx = fmaxf(mx, av[k]);
        float ss = 0.f;
#pragma unroll
        for (int k = 0; k < NC; k++) { av[k] = __expf(av[k] - mx); ss += av[k]; }
        const float inv = 1.f / ss;
        if (grp == 0)      { cw0 = av[0];  cw1 = av[1];  cw2 = av[2];  cw3 = av[3];  }
        else if (grp == 1) { cw0 = av[4];  cw1 = av[5];  cw2 = av[6];  cw3 = av[7];  }
        else if (grp == 2) { cw0 = av[8];  cw1 = av[9];  cw2 = av[10]; cw3 = av[11]; }
        else               { cw0 = av[12]; cw1 = av[13]; cw2 = av[14]; cw3 = av[15]; }
        cw0 *= inv; cw1 *= inv; cw2 *= inv; cw3 *= inv;
    }
    // xs: NO sync (reads xT + same-wave regs). wave (grp, rq): caps grp*4..+3,
    // rows rq*64..+63, lane = i; cw for row rq*64+nl lives in lane nl.
    {
        float s0 = 0.f, s1 = 0.f, s2 = 0.f, s3 = 0.f;
#pragma unroll
        for (int nl = 0; nl < 64; nl++) {
            const float xv = xT[(rq * 64 + nl) * XS + lane];   // coalesced b32
            s0 += rdlane_f(cw0, nl) * xv;
            s1 += rdlane_f(cw1, nl) * xv;
            s2 += rdlane_f(cw2, nl) * xv;
            s3 += rdlane_f(cw3, nl) * xv;
        }
        *reinterpret_cast<float4*>(&pSm[(rq * 64 + lane) * AS + grp * 4]) =
            make_float4(s0, s1, s2, s3);
    }
    __syncthreads();
    // reduce the 4 rq partials: thread (c = wave, i = lane) -> val for o = tid
    return pSm[(0 * 64 + lane) * AS + wave] + pSm[(1 * 64 + lane) * AS + wave] +
           pSm[(2 * 64 + lane) * AS + wave] + pSm[(3 * 64 + lane) * AS + wave];
}

// s = red @ W[c] (+scale) -> squash -> vSm (or out); then wv -> wSm
// modeRed0: red[i] (colsum); else red[c][i].
__device__ __forceinline__ void caps_sv(const float* __restrict__ W, const float* redSm,
                                        float* vSm, int tid, bool modeRed0, bool toOut,
                                        float* __restrict__ outp, int b, int q) {
    if (tid < 512) {
        const int c = tid >> 5, dd = tid & 31;
        const float* Wc = W + c * (IDIM * DC) + dd;
        float s = 0.f;
#pragma unroll 8
        for (int i = 0; i < IDIM; i++) {
            const float rv = modeRed0 ? redSm[i] : redSm[c * 64 + i];
            s += rv * Wc[i * DC];
        }
        if (modeRed0) s *= 0.0625f;
        float n2 = s * s;
#pragma unroll
        for (int m = 16; m >= 1; m >>= 1) n2 += __shfl_xor(n2, m);  // 32-lane half
        const float g = (n2 / (1.f + n2)) / (sqrtf(n2) + 1e-8f);
        if (toOut) { if (q == 0) outp[b * (NC * DC) + c * DC + dd] = g * s; }
        else       vSm[c * 36 + dd] = g * s;
    }
    __syncthreads();
}

__device__ __forceinline__ float caps_wv(const float* __restrict__ W, const float* vSm,
                                         int tid) {
    const int i = tid >> 4, c = tid & 15;   // 64 i x 16 c; out index == tid
    const float4* Wr = reinterpret_cast<const float4*>(W + (size_t)(c * IDIM + i) * DC);
    const float4* vv = reinterpret_cast<const float4*>(&vSm[c * 36]);
    float acc = 0.f;
#pragma unroll
    for (int dq = 0; dq < 8; dq++) {
        const float4 wq = Wr[dq], vq = vv[dq];
        acc += wq.x * vq.x + wq.y * vq.y + wq.z * vq.z + wq.w * vq.w;
    }
    return acc;
}

// ---- phase 1: stage -> colsum (1 spin round) -> caps0 -> route1 -> sp1 (plain)
__global__ __launch_bounds__(NTHR, 1)
void k_phase1(const float* __restrict__ x, const float* __restrict__ W,
              int* __restrict__ cnt, float* __restrict__ cs,
              float* __restrict__ sp1, float* __restrict__ wv0) {
    const int b = blockIdx.x & 63, q = blockIdx.x >> 6;   // XCD co-location
    const int tid = threadIdx.x, lane = tid & 63, wave = tid >> 6;
    const int row = tid & 255, grp = tid >> 8, rq = wave & 3;

    __shared__ float __align__(16) xT[QR * XS];
    __shared__ float __align__(16) aSmT[QR * AS];
    __shared__ float __align__(16) pSm[4 * 64 * AS];
    __shared__ float __align__(16) wSm[IDIM * AS];
    __shared__ float redSm[NC * IDIM];
    __shared__ float __align__(16) vSm[NC * 36];

    stage_x(x, xT, b, q, tid);
    __syncthreads();

    // colsum partial: wave w sums rows w*16..+15 at i = lane (coalesced)
    {
        float s = 0.f;
#pragma unroll
        for (int t = 0; t < 16; t++) s += xT[(wave * 16 + t) * XS + lane];
        redSm[wave * 64 + lane] = s;
    }
    __syncthreads();
    if (tid < 64) {
        float r = 0.f;
#pragma unroll
        for (int w2 = 0; w2 < 16; w2++) r += redSm[w2 * 64 + tid];
        st_agent(&cs[(b * NQ + q) * 64 + tid], r);
    }
    __syncthreads();                      // drains stores before signal
    if (tid == 0)
        __hip_atomic_fetch_add(&cnt[b * 16], 1, __ATOMIC_RELEASE, __HIP_MEMORY_SCOPE_AGENT);
    if (tid == 0)
        while (__hip_atomic_load(&cnt[b * 16], __ATOMIC_ACQUIRE,
                                 __HIP_MEMORY_SCOPE_AGENT) < NQ)
            __builtin_amdgcn_s_sleep(1);
    __syncthreads();
    if (tid < 64) {
        float r = 0.f;
#pragma unroll
        for (int k = 0; k < NQ; k++) r += ld_agent(&cs[(b * NQ + k) * 64 + tid]);
        redSm[tid] = r;
    }
    __syncthreads();

    // caps0: v0 -> wSm; q0 persists wv0 (plain store; kernel boundary syncs)
    caps_sv(W, redSm, vSm, tid, true, false, nullptr, b, q);
    {
        const float acc = caps_wv(W, vSm, tid);
        wSm[(tid >> 4) * AS + (tid & 15)] = acc;
        if (q == 0) wv0[b * 1024 + tid] = acc;
    }
    __syncthreads();

    // route1 -> sp1 with PLAIN coalesced stores
    const float val = route_pass(xT, wSm, aSmT, pSm, tid, lane, wave, row, grp, rq);
    sp1[(size_t)(b * NQ + q) * 1024 + tid] = val;
}

// ---- phase 2: stage -> reduce sp1 (plain) -> caps1 -> route2 -> sp2 (agent)
//      -> 1 spin round -> q0: reduce + caps2 -> out
__global__ __launch_bounds__(NTHR, 1)
void k_phase2(const float* __restrict__ x, const float* __restrict__ W,
              float* __restrict__ out, int* __restrict__ cnt,
              const float* __restrict__ sp1, float* __restrict__ sp2,
              const float* __restrict__ wv0) {
    const int b = blockIdx.x & 63, q = blockIdx.x >> 6;
    const int tid = threadIdx.x, lane = tid & 63, wave = tid >> 6;
    const int row = tid & 255, grp = tid >> 8, rq = wave & 3;

    __shared__ float __align__(16) xT[QR * XS];
    __shared__ float __align__(16) aSmT[QR * AS];
    __shared__ float __align__(16) pSm[4 * 64 * AS];
    __shared__ float __align__(16) wSm[IDIM * AS];
    __shared__ float redSm[NC * IDIM];
    __shared__ float __align__(16) vSm[NC * 36];

    stage_x(x, xT, b, q, tid);
    // reduce sp1 across the 4 sibling blocks (PLAIN loads, L2-warm)
    {
        float r = 0.f;
#pragma unroll
        for (int k = 0; k < NQ; k++) r += sp1[(size_t)(b * NQ + k) * 1024 + tid];
        redSm[tid] = r;
    }
    __syncthreads();

    // caps1: v1 -> wSm = wv(v1) + wv0 (logit linearity: wv_eff)
    caps_sv(W, redSm, vSm, tid, false, false, nullptr, b, q);
    wSm[(tid >> 4) * AS + (tid & 15)] = caps_wv(W, vSm, tid) + wv0[b * 1024 + tid];
    __syncthreads();

    // route2 -> sp2 (agent scope: consumed within this kernel by q0)
    const float val = route_pass(xT, wSm, aSmT, pSm, tid, lane, wave, row, grp, rq);
    st_agent(&sp2[(size_t)(b * NQ + q) * 1024 + tid], val);

    __syncthreads();                      // drains sp2 stores before signal
    if (tid == 0)
        __hip_atomic_fetch_add(&cnt[b * 16], 1, __ATOMIC_RELEASE, __HIP_MEMORY_SCOPE_AGENT);
    if (q != 0) return;                   // producers done
    if (tid == 0)
        while (__hip_atomic_load(&cnt[b * 16], __ATOMIC_ACQUIRE,
                                 __HIP_MEMORY_SCOPE_AGENT) < 2 * NQ)
            __builtin_amdgcn_s_sleep(1);
    __syncthreads();
    {
        float r = val;                    // own partial from registers
#pragma unroll
        for (int k = 1; k < NQ; k++) r += ld_agent(&sp2[(size_t)(b * NQ + k) * 1024 + tid]);
        redSm[tid] = r;
    }
    __syncthreads();
    caps_sv(W, redSm, vSm, tid, false, true, out, b, q);   // final squash -> out
}

extern "C" void kernel_launch(void* const* d_in, const int* in_sizes, int n_in,
                              void* d_out, int out_size, void* d_ws, size_t ws_size,
                              hipStream_t stream) {
    const float* x = (const float*)d_in[0];    // [64,1024,64]
    const float* W = (const float*)d_in[1];    // [16,64,32]
    float* out = (float*)d_out;                // [64,16,32]
    float* ws = (float*)d_ws;

    int*   cnt = (int*)(ws + WS_CNT);
    float* cs  = ws + WS_CS;
    float* sp1 = ws + WS_SP1;
    float* sp2 = ws + WS_SP2;
    float* wv0 = ws + WS_WV0;

    k_reset<<<1, 1024, 0, stream>>>(cnt);
    k_phase1<<<B_SZ * NQ, NTHR, 0, stream>>>(x, W, cnt, cs, sp1, wv0);
    k_phase2<<<B_SZ * NQ, NTHR, 0, stream>>>(x, W, out, cnt, sp1, sp2, wv0);
}

// Round 17
// 43.993 us; speedup vs baseline: 1.7883x; 1.0935x over previous
//
#include <hip/hip_runtime.h>
#include <math.h>

// Problem constants (fixed by reference setup_inputs)
#define B_SZ 64
#define N_IN 1024
#define IDIM 64
#define NC   16
#define DC   32
#define NQ   4      // blocks per batch
#define QR   256    // rows per block
#define NTHR 1024   // 16 waves
#define XS   68     // xT row stride [n][i]: 68%32=4 -> b128 floor patterns
#define AS   20     // aSmT / pSm / wSm row stride

// Workspace (floats). NOTHING needs zero-init; no atomics, no counters,
// no spin barriers. All cross-block reductions cross kernel boundaries.
//  cs  : [64][4][64]   @ 0       colsum partials (plain)
//  sp1 : [64][4][1024] @ 16384   xs partials iter 1 (plain)
//  sp2 : [64][4][1024] @ 278528  xs partials iter 2 (plain)
//  wv0 : [64][1024]    @ 540672  wv(v0) (plain; q0 writes in K1, read in K2)
#define WS_CS  0
#define WS_SP1 16384
#define WS_SP2 278528
#define WS_WV0 540672

__device__ __forceinline__ float rdlane_f(float v, int l) {
    return __int_as_float(__builtin_amdgcn_readlane(__float_as_int(v), l));
}

// ---- shared building blocks (round-12/16-proven inner code) ----

// stage 256 rows into [n][i] tile: 4 conflict-free ds_write_b128/thread
__device__ __forceinline__ void stage_x(const float* __restrict__ x, float* xT,
                                        int b, int q, int tid) {
    const float4* xb4 = reinterpret_cast<const float4*>(x + ((size_t)b * N_IN + q * QR) * IDIM);
#pragma unroll
    for (int m = 0; m < 4; m++) {
        const int f = tid + m * NTHR;
        const float4 v4 = xb4[f];
        const int n = f >> 4, i0 = (f & 15) * 4;
        *reinterpret_cast<float4*>(&xT[n * XS + i0]) = v4;
    }
}

// routing pass: agreement(b128+readlane) -> softmax(regs) -> xs(readlane) -> val
__device__ __forceinline__ float route_pass(const float* xT, const float* wSm,
                                            float* aSmT, float* pSm,
                                            int tid, int lane, int wave,
                                            int row, int grp, int rq) {
    const float4 wr4 = *reinterpret_cast<const float4*>(&wSm[lane * AS + grp * 4]);
    {   // agreement: caps grp*4..+3 for row; 16 b128 + readlane-fma
        float a0 = 0.f, a1 = 0.f, a2 = 0.f, a3 = 0.f;
#pragma unroll
        for (int iq = 0; iq < 16; iq++) {
            const float4 xv = *reinterpret_cast<const float4*>(&xT[row * XS + iq * 4]);
#pragma unroll
            for (int j = 0; j < 4; j++) {
                const int i = iq * 4 + j;
                const float xc = (j == 0) ? xv.x : (j == 1) ? xv.y
                               : (j == 2) ? xv.z : xv.w;
                a0 += rdlane_f(wr4.x, i) * xc;
                a1 += rdlane_f(wr4.y, i) * xc;
                a2 += rdlane_f(wr4.z, i) * xc;
                a3 += rdlane_f(wr4.w, i) * xc;
            }
        }
        *reinterpret_cast<float4*>(&aSmT[row * AS + grp * 4]) =
            make_float4(a0, a1, a2, a3);
    }
    __syncthreads();
    // softmax over 16 caps per row; cw via uniform grp if-chain (regs only)
    float cw0, cw1, cw2, cw3;
    {
        const float4 q0 = *reinterpret_cast<const float4*>(&aSmT[row * AS + 0]);
        const float4 q1 = *reinterpret_cast<const float4*>(&aSmT[row * AS + 4]);
        const float4 q2 = *reinterpret_cast<const float4*>(&aSmT[row * AS + 8]);
        const float4 q3 = *reinterpret_cast<const float4*>(&aSmT[row * AS + 12]);
        float av[NC] = {q0.x, q0.y, q0.z, q0.w, q1.x, q1.y, q1.z, q1.w,
                        q2.x, q2.y, q2.z, q2.w, q3.x, q3.y, q3.z, q3.w};
        float mx = av[0];
#pragma unroll
        for (int k = 1; k < NC; k++) mx = fmaxf(mx, av[k]);
        float ss = 0.f;
#pragma unroll
        for (int k = 0; k < NC; k++) { av[k] = __expf(av[k] - mx); ss += av[k]; }
        const float inv = 1.f / ss;
        if (grp == 0)      { cw0 = av[0];  cw1 = av[1];  cw2 = av[2];  cw3 = av[3];  }
        else if (grp == 1) { cw0 = av[4];  cw1 = av[5];  cw2 = av[6];  cw3 = av[7];  }
        else if (grp == 2) { cw0 = av[8];  cw1 = av[9];  cw2 = av[10]; cw3 = av[11]; }
        else               { cw0 = av[12]; cw1 = av[13]; cw2 = av[14]; cw3 = av[15]; }
        cw0 *= inv; cw1 *= inv; cw2 *= inv; cw3 *= inv;
    }
    // xs: NO sync (reads xT + same-wave regs). wave (grp, rq): caps grp*4..+3,
    // rows rq*64..+63, lane = i; cw for row rq*64+nl lives in lane nl.
    {
        float s0 = 0.f, s1 = 0.f, s2 = 0.f, s3 = 0.f;
#pragma unroll
        for (int nl = 0; nl < 64; nl++) {
            const float xv = xT[(rq * 64 + nl) * XS + lane];   // coalesced b32
            s0 += rdlane_f(cw0, nl) * xv;
            s1 += rdlane_f(cw1, nl) * xv;
            s2 += rdlane_f(cw2, nl) * xv;
            s3 += rdlane_f(cw3, nl) * xv;
        }
        *reinterpret_cast<float4*>(&pSm[(rq * 64 + lane) * AS + grp * 4]) =
            make_float4(s0, s1, s2, s3);
    }
    __syncthreads();
    // reduce the 4 rq partials: thread (c = wave, i = lane) -> val for o = tid
    return pSm[(0 * 64 + lane) * AS + wave] + pSm[(1 * 64 + lane) * AS + wave] +
           pSm[(2 * 64 + lane) * AS + wave] + pSm[(3 * 64 + lane) * AS + wave];
}

// s = red @ W[c] (+scale) -> squash -> vSm (or out)
__device__ __forceinline__ void caps_sv(const float* __restrict__ W, const float* redSm,
                                        float* vSm, int tid, bool modeRed0, bool toOut,
                                        float* __restrict__ outp, int b) {
    if (tid < 512) {
        const int c = tid >> 5, dd = tid & 31;
        const float* Wc = W + c * (IDIM * DC) + dd;
        float s = 0.f;
#pragma unroll 8
        for (int i = 0; i < IDIM; i++) {
            const float rv = modeRed0 ? redSm[i] : redSm[c * 64 + i];
            s += rv * Wc[i * DC];
        }
        if (modeRed0) s *= 0.0625f;
        float n2 = s * s;
#pragma unroll
        for (int m = 16; m >= 1; m >>= 1) n2 += __shfl_xor(n2, m);  // 32-lane half
        const float g = (n2 / (1.f + n2)) / (sqrtf(n2) + 1e-8f);
        if (toOut) outp[b * (NC * DC) + c * DC + dd] = g * s;
        else       vSm[c * 36 + dd] = g * s;
    }
    __syncthreads();
}

__device__ __forceinline__ float caps_wv(const float* __restrict__ W, const float* vSm,
                                         int tid) {
    const int i = tid >> 4, c = tid & 15;   // 64 i x 16 c; out index == tid
    const float4* Wr = reinterpret_cast<const float4*>(W + (size_t)(c * IDIM + i) * DC);
    const float4* vv = reinterpret_cast<const float4*>(&vSm[c * 36]);
    float acc = 0.f;
#pragma unroll
    for (int dq = 0; dq < 8; dq++) {
        const float4 wq = Wr[dq], vq = vv[dq];
        acc += wq.x * vq.x + wq.y * vq.y + wq.z * vq.z + wq.w * vq.w;
    }
    return acc;
}

// ---- K0: colsum partials straight from global (streams x, warms L3)
__global__ __launch_bounds__(256) void k_colsum(const float* __restrict__ x,
                                                float* __restrict__ cs) {
    const int b = blockIdx.y, q = blockIdx.x;
    const int tid = threadIdx.x;
    const float4* xb4 = reinterpret_cast<const float4*>(x + ((size_t)b * N_IN + q * QR) * IDIM);
    // thread: rows (tid>>4)+m*16, column block i0 = (tid&15)*4
    float4 s4 = {0.f, 0.f, 0.f, 0.f};
#pragma unroll
    for (int m = 0; m < 16; m++) {
        const float4 v4 = xb4[tid + m * 256];
        s4.x += v4.x; s4.y += v4.y; s4.z += v4.z; s4.w += v4.w;
    }
    __shared__ float red[16][64];
    const int g = tid >> 4, i0 = (tid & 15) * 4;
    red[g][i0 + 0] = s4.x; red[g][i0 + 1] = s4.y;
    red[g][i0 + 2] = s4.z; red[g][i0 + 3] = s4.w;
    __syncthreads();
    if (tid < 64) {
        float r = 0.f;
#pragma unroll
        for (int k = 0; k < 16; k++) r += red[k][tid];
        cs[(b * NQ + q) * 64 + tid] = r;
    }
}

// ---- K1: stage + reduce cs -> caps0 -> route1 -> sp1 (all plain)
__global__ __launch_bounds__(NTHR, 1)
void k_iter1(const float* __restrict__ x, const float* __restrict__ W,
             const float* __restrict__ cs, float* __restrict__ sp1,
             float* __restrict__ wv0) {
    const int b = blockIdx.x & 63, q = blockIdx.x >> 6;
    const int tid = threadIdx.x, lane = tid & 63, wave = tid >> 6;
    const int row = tid & 255, grp = tid >> 8, rq = wave & 3;

    __shared__ float __align__(16) xT[QR * XS];
    __shared__ float __align__(16) aSmT[QR * AS];
    __shared__ float __align__(16) pSm[4 * 64 * AS];
    __shared__ float __align__(16) wSm[IDIM * AS];
    __shared__ float redSm[NC * IDIM];
    __shared__ float __align__(16) vSm[NC * 36];

    stage_x(x, xT, b, q, tid);                 // L3-warm from K0
    if (tid < 64) {
        float r = 0.f;
#pragma unroll
        for (int k = 0; k < NQ; k++) r += cs[(b * NQ + k) * 64 + tid];
        redSm[tid] = r;
    }
    __syncthreads();
    caps_sv(W, redSm, vSm, tid, true, false, nullptr, b);
    {
        const float acc = caps_wv(W, vSm, tid);
        wSm[(tid >> 4) * AS + (tid & 15)] = acc;
        if (q == 0) wv0[b * 1024 + tid] = acc;
    }
    __syncthreads();
    const float val = route_pass(xT, wSm, aSmT, pSm, tid, lane, wave, row, grp, rq);
    sp1[(size_t)(b * NQ + q) * 1024 + tid] = val;
}

// ---- K2: stage + reduce sp1 -> caps1 (wv_eff = wv(v1)+wv0) -> route2 -> sp2
__global__ __launch_bounds__(NTHR, 1)
void k_iter2(const float* __restrict__ x, const float* __restrict__ W,
             const float* __restrict__ sp1, float* __restrict__ sp2,
             const float* __restrict__ wv0) {
    const int b = blockIdx.x & 63, q = blockIdx.x >> 6;
    const int tid = threadIdx.x, lane = tid & 63, wave = tid >> 6;
    const int row = tid & 255, grp = tid >> 8, rq = wave & 3;

    __shared__ float __align__(16) xT[QR * XS];
    __shared__ float __align__(16) aSmT[QR * AS];
    __shared__ float __align__(16) pSm[4 * 64 * AS];
    __shared__ float __align__(16) wSm[IDIM * AS];
    __shared__ float redSm[NC * IDIM];
    __shared__ float __align__(16) vSm[NC * 36];

    stage_x(x, xT, b, q, tid);                 // same grid mapping -> L2-resident
    {
        float r = 0.f;
#pragma unroll
        for (int k = 0; k < NQ; k++) r += sp1[(size_t)(b * NQ + k) * 1024 + tid];
        redSm[tid] = r;
    }
    __syncthreads();
    caps_sv(W, redSm, vSm, tid, false, false, nullptr, b);
    wSm[(tid >> 4) * AS + (tid & 15)] = caps_wv(W, vSm, tid) + wv0[b * 1024 + tid];
    __syncthreads();
    const float val = route_pass(xT, wSm, aSmT, pSm, tid, lane, wave, row, grp, rq);
    sp2[(size_t)(b * NQ + q) * 1024 + tid] = val;
}

// ---- K3: reduce sp2 -> final squash -> out
__global__ __launch_bounds__(NTHR) void k_final(const float* __restrict__ sp2,
                                                const float* __restrict__ W,
                                                float* __restrict__ out) {
    const int b = blockIdx.x, tid = threadIdx.x;
    __shared__ float redSm[NC * IDIM];
    __shared__ float __align__(16) vSm[NC * 36];
    {
        float r = 0.f;
#pragma unroll
        for (int k = 0; k < NQ; k++) r += sp2[(size_t)(b * NQ + k) * 1024 + tid];
        redSm[tid] = r;
    }
    __syncthreads();
    caps_sv(W, redSm, vSm, tid, false, true, out, b);
}

extern "C" void kernel_launch(void* const* d_in, const int* in_sizes, int n_in,
                              void* d_out, int out_size, void* d_ws, size_t ws_size,
                              hipStream_t stream) {
    const float* x = (const float*)d_in[0];    // [64,1024,64]
    const float* W = (const float*)d_in[1];    // [16,64,32]
    float* out = (float*)d_out;                // [64,16,32]
    float* ws = (float*)d_ws;

    float* cs  = ws + WS_CS;
    float* sp1 = ws + WS_SP1;
    float* sp2 = ws + WS_SP2;
    float* wv0 = ws + WS_WV0;

    k_colsum<<<dim3(NQ, B_SZ), 256, 0, stream>>>(x, cs);
    k_iter1<<<B_SZ * NQ, NTHR, 0, stream>>>(x, W, cs, sp1, wv0);
    k_iter2<<<B_SZ * NQ, NTHR, 0, stream>>>(x, W, sp1, sp2, wv0);
    k_final<<<B_SZ, NTHR, 0, stream>>>(sp2, W, out);
}